// Round 2
// baseline (3853.247 us; speedup 1.0000x reference)
//
#include <hip/hip_runtime.h>

#define DEV __device__ __forceinline__

using f32x4  = __attribute__((ext_vector_type(4))) float;
using bf16x8 = __attribute__((ext_vector_type(8))) short;

static constexpr int kBT = 4;
static constexpr int kLQ = 5376;
static constexpr long kMrows = (long)kBT * kLQ;   // 21504

DEV unsigned short f2b(float f) {
  unsigned u = __builtin_bit_cast(unsigned, f);
  u = u + 0x7fffu + ((u >> 16) & 1u);
  return (unsigned short)(u >> 16);
}
DEV float b2f(unsigned short s) {
  unsigned u = ((unsigned)s) << 16;
  return __builtin_bit_cast(float, u);
}

// ---------------------------------------------------------------------------
// Generic MFMA GEMM: C[M][N] = A[M][K] * B^T  (Bt is [N][K] bf16) + bias
// EPI: 0 = fp32 out, 1 = bf16 out, 2 = relu -> bf16 out
// ADD2: A := A + A2 (both fp32)     ABF16: A is bf16
// Tile 64x64, BK=32, 4 waves (2x2), each wave 32x32 via 2x2 16x16x32 MFMAs.
// ---------------------------------------------------------------------------
template<int EPI, bool ADD2, bool ABF16>
__global__ __launch_bounds__(256) void gemm64(
    const void* __restrict__ Ap, const void* __restrict__ A2p,
    const unsigned short* __restrict__ Bt, const float* __restrict__ bias,
    void* __restrict__ Cp, int M, int N, int K)
{
  __shared__ unsigned short As[64][40];
  __shared__ unsigned short Bs[64][40];
  const int tid = threadIdx.x;
  const int m0 = blockIdx.x * 64, n0 = blockIdx.y * 64;
  const int lane = tid & 63, wid = tid >> 6;
  const int wr = wid >> 1, wc = wid & 1;
  const int sr = tid >> 2, sk = (tid & 3) * 8;
  const int l15 = lane & 15, lg = lane >> 4;

  f32x4 acc[2][2];
#pragma unroll
  for (int i = 0; i < 2; i++)
#pragma unroll
    for (int j = 0; j < 2; j++) acc[i][j] = f32x4{0.f, 0.f, 0.f, 0.f};

  const long arow = m0 + sr;
  const int  brow = n0 + sr;
  const bool bvalid = brow < N;

  for (int k0 = 0; k0 < K; k0 += 32) {
    if (ABF16) {
      const unsigned short* A = (const unsigned short*)Ap;
      uint4 v = *(const uint4*)(A + arow * K + k0 + sk);
      *(uint4*)&As[sr][sk] = v;
    } else {
      const float* A = (const float*)Ap + arow * K + k0 + sk;
      float a[8];
#pragma unroll
      for (int j = 0; j < 8; j++) a[j] = A[j];
      if (ADD2) {
        const float* A2 = (const float*)A2p + arow * K + k0 + sk;
#pragma unroll
        for (int j = 0; j < 8; j++) a[j] += A2[j];
      }
      unsigned short t[8];
#pragma unroll
      for (int j = 0; j < 8; j++) t[j] = f2b(a[j]);
      *(uint4*)&As[sr][sk] = *(const uint4*)t;
    }
    uint4 bv = {0u, 0u, 0u, 0u};
    if (bvalid) bv = *(const uint4*)(Bt + (long)brow * K + k0 + sk);
    *(uint4*)&Bs[sr][sk] = bv;
    __syncthreads();

    bf16x8 af[2], bfv[2];
    af[0]  = *(const bf16x8*)&As[wr * 32 +      l15][lg * 8];
    af[1]  = *(const bf16x8*)&As[wr * 32 + 16 + l15][lg * 8];
    bfv[0] = *(const bf16x8*)&Bs[wc * 32 +      l15][lg * 8];
    bfv[1] = *(const bf16x8*)&Bs[wc * 32 + 16 + l15][lg * 8];
#pragma unroll
    for (int mi = 0; mi < 2; mi++)
#pragma unroll
      for (int ni = 0; ni < 2; ni++)
        acc[mi][ni] = __builtin_amdgcn_mfma_f32_16x16x32_bf16(
            af[mi], bfv[ni], acc[mi][ni], 0, 0, 0);
    __syncthreads();
  }

#pragma unroll
  for (int mi = 0; mi < 2; mi++)
#pragma unroll
    for (int ni = 0; ni < 2; ni++) {
      int col = n0 + wc * 32 + ni * 16 + l15;
      if (col >= N) continue;
      float bb = bias[col];
#pragma unroll
      for (int r = 0; r < 4; r++) {
        long row = m0 + wr * 32 + mi * 16 + lg * 4 + r;
        float v = acc[mi][ni][r] + bb;
        if (EPI == 2) v = fmaxf(v, 0.f);
        if (EPI == 0) ((float*)Cp)[row * N + col] = v;
        else ((unsigned short*)Cp)[row * N + col] = f2b(v);
      }
    }
}

// ---------------------------------------------------------------------------
// 3x3 conv as implicit GEMM over xb (BT,128,128,256) bf16, tap-major K=2304.
// Accumulates relu(conv + bias) into mask (B=2, 256, T=2, 128, 128) fp32.
// ---------------------------------------------------------------------------
__global__ __launch_bounds__(256) void conv3x3_acc(
    const unsigned short* __restrict__ xb, const unsigned short* __restrict__ wT,
    const float* __restrict__ bias, float* __restrict__ mask)
{
  __shared__ unsigned short As[64][40];
  __shared__ unsigned short Bs[64][40];
  const int tid = threadIdx.x;
  const int bt = blockIdx.z;
  const int p0 = blockIdx.x * 64, c0 = blockIdx.y * 64;
  const int y = p0 >> 7, x0 = p0 & 127;
  const int lane = tid & 63, wid = tid >> 6, wr = wid >> 1, wc = wid & 1;
  const int sr = tid >> 2, sk = (tid & 3) * 8;
  const int l15 = lane & 15, lg = lane >> 4;

  f32x4 acc[2][2];
#pragma unroll
  for (int i = 0; i < 2; i++)
#pragma unroll
    for (int j = 0; j < 2; j++) acc[i][j] = f32x4{0.f, 0.f, 0.f, 0.f};

  const unsigned short* xbb = xb + (long)bt * (128 * 128 * 256);
  for (int s = 0; s < 72; s++) {
    const int t = s >> 3;
    const int ci = (s & 7) * 32 + sk;
    const int dy = t / 3 - 1, dx = t % 3 - 1;
    const int yy = y + dy, xx = x0 + sr + dx;
    uint4 av = {0u, 0u, 0u, 0u};
    if ((unsigned)yy < 128u && (unsigned)xx < 128u)
      av = *(const uint4*)(xbb + ((long)yy * 128 + xx) * 256 + ci);
    *(uint4*)&As[sr][sk] = av;
    uint4 bv = *(const uint4*)(wT + ((long)(c0 + sr) * 9 + t) * 256 + ci);
    *(uint4*)&Bs[sr][sk] = bv;
    __syncthreads();

    bf16x8 af[2], bfv[2];
    af[0]  = *(const bf16x8*)&As[wr * 32 +      l15][lg * 8];
    af[1]  = *(const bf16x8*)&As[wr * 32 + 16 + l15][lg * 8];
    bfv[0] = *(const bf16x8*)&Bs[wc * 32 +      l15][lg * 8];
    bfv[1] = *(const bf16x8*)&Bs[wc * 32 + 16 + l15][lg * 8];
#pragma unroll
    for (int mi = 0; mi < 2; mi++)
#pragma unroll
      for (int ni = 0; ni < 2; ni++)
        acc[mi][ni] = __builtin_amdgcn_mfma_f32_16x16x32_bf16(
            af[mi], bfv[ni], acc[mi][ni], 0, 0, 0);
    __syncthreads();
  }

  const int b = bt >> 1, tt = bt & 1;
#pragma unroll
  for (int mi = 0; mi < 2; mi++)
#pragma unroll
    for (int ni = 0; ni < 2; ni++) {
      int co = c0 + wc * 32 + ni * 16 + l15;
      float bb = bias[co];
#pragma unroll
      for (int r = 0; r < 4; r++) {
        int p = p0 + wr * 32 + mi * 16 + lg * 4 + r;
        float v = fmaxf(acc[mi][ni][r] + bb, 0.f);
        long idx = (((long)b * 256 + co) * 2 + tt) * 16384 + p;
        mask[idx] += v;
      }
    }
}

// ---------------------------------------------------------------------------
// Deformable-attention bilinear sampling. One block per (bt,q); thread=(h,d).
// ---------------------------------------------------------------------------
__global__ __launch_bounds__(256) void deform_sample(
    const float* __restrict__ offp, const float* __restrict__ awp,
    const unsigned short* __restrict__ vp, float* __restrict__ attn)
{
  const int m = blockIdx.x;
  const int bt = m / kLQ, q = m % kLQ;
  const int tid = threadIdx.x;
  const int h = tid >> 5, d = tid & 31;
  int pq, Wq;
  if (q < 256)       { pq = q;        Wq = 16; }
  else if (q < 1280) { pq = q - 256;  Wq = 32; }
  else               { pq = q - 1280; Wq = 64; }
  const float refx = ((pq % Wq) + 0.5f) / Wq;
  const float refy = ((pq / Wq) + 0.5f) / Wq;
  const int starts[3] = {0, 256, 1280};
  const int dims[3]   = {16, 32, 64};
  const float* offr = offp + (long)m * 192 + h * 24;
  const float* awr  = awp  + (long)m * 96  + h * 12;
  const unsigned short* vb = vp + ((long)bt * kLQ) * 256 + h * 32 + d;
  float acc = 0.f;
#pragma unroll
  for (int l = 0; l < 3; l++) {
    const int Wl = dims[l];
    const float inv = 1.f / (float)Wl;
    const int st = starts[l];
#pragma unroll
    for (int p = 0; p < 4; p++) {
      float ox = offr[l * 8 + p * 2], oy = offr[l * 8 + p * 2 + 1];
      float a  = awr[l * 4 + p];
      float fxp = (refx + ox * inv) * Wl - 0.5f;
      float fyp = (refy + oy * inv) * Wl - 0.5f;
      float x0f = floorf(fxp), y0f = floorf(fyp);
      int x0 = (int)x0f, y0 = (int)y0f;
      float fx = fxp - x0f, fy = fyp - y0f;
      float s = 0.f;
#pragma unroll
      for (int cy = 0; cy < 2; cy++)
#pragma unroll
        for (int cx = 0; cx < 2; cx++) {
          int ix = x0 + cx, iy = y0 + cy;
          if ((unsigned)ix < (unsigned)Wl && (unsigned)iy < (unsigned)Wl) {
            float w = (cx ? fx : 1.f - fx) * (cy ? fy : 1.f - fy);
            s += w * b2f(vb[((long)(st + iy * Wl + ix)) * 256]);
          }
        }
      acc += a * s;
    }
  }
  attn[(long)m * 256 + tid] = acc;
}

// softmax over 12 logits per (row,head), in place
__global__ __launch_bounds__(256) void softmax12(float* __restrict__ aw, int total)
{
  int i = blockIdx.x * 256 + threadIdx.x;
  if (i >= total) return;
  float* p = aw + (long)i * 12;
  float mx = p[0];
#pragma unroll
  for (int j = 1; j < 12; j++) mx = fmaxf(mx, p[j]);
  float s = 0.f;
#pragma unroll
  for (int j = 0; j < 12; j++) { float e = __expf(p[j] - mx); p[j] = e; s += e; }
  float invs = 1.f / s;
#pragma unroll
  for (int j = 0; j < 12; j++) p[j] *= invs;
}

// out = LN(out + delta) * g + b, per row of 256
__global__ __launch_bounds__(256) void ln_residual(
    float* __restrict__ out, const float* __restrict__ delta,
    const float* __restrict__ g, const float* __restrict__ b)
{
  const long m = blockIdx.x;
  const int c = threadIdx.x;
  float x = out[m * 256 + c] + delta[m * 256 + c];
  __shared__ float red[4], red2[4];
  float s = x;
#pragma unroll
  for (int o = 32; o > 0; o >>= 1) s += __shfl_down(s, o);
  if ((c & 63) == 0) red[c >> 6] = s;
  __syncthreads();
  float mean = (red[0] + red[1] + red[2] + red[3]) * (1.f / 256.f);
  float dx = x - mean;
  float s2 = dx * dx;
#pragma unroll
  for (int o = 32; o > 0; o >>= 1) s2 += __shfl_down(s2, o);
  if ((c & 63) == 0) red2[c >> 6] = s2;
  __syncthreads();
  float var = (red2[0] + red2[1] + red2[2] + red2[3]) * (1.f / 256.f);
  out[m * 256 + c] = dx * rsqrtf(var + 1e-5f) * g[c] + b[c];
}

// xb[bt,y,x,c] += bilinear_resize(output[:,1280:] as 64x64)(y,x,c)
__global__ __launch_bounds__(256) void resize_add(
    unsigned short* __restrict__ xb, const float* __restrict__ out)
{
  const int pix = blockIdx.x;          // bt*16384 + y*128 + x
  const int bt = pix >> 14;
  const int y = (pix >> 7) & 127, x = pix & 127;
  const int c = threadIdx.x;
  float sy = y * 0.5f - 0.25f, sx = x * 0.5f - 0.25f;
  float y0f = floorf(sy), x0f = floorf(sx);
  float fy = sy - y0f, fx = sx - x0f;
  int y0 = min(63, max(0, (int)y0f)), y1 = min(63, max(0, (int)y0f + 1));
  int x0 = min(63, max(0, (int)x0f)), x1 = min(63, max(0, (int)x0f + 1));
  const float* base = out + ((long)bt * kLQ + 1280) * 256 + c;
  float v00 = base[(long)(y0 * 64 + x0) * 256];
  float v01 = base[(long)(y0 * 64 + x1) * 256];
  float v10 = base[(long)(y1 * 64 + x0) * 256];
  float v11 = base[(long)(y1 * 64 + x1) * 256];
  float v = (1.f - fy) * ((1.f - fx) * v00 + fx * v01)
          + fy * ((1.f - fx) * v10 + fx * v11);
  long idx = (long)pix * 256 + c;
  xb[idx] = f2b(b2f(xb[idx]) + v);
}

// weight transpose+convert: outT[l][n][k] = bf16(in[l][k][n])
__global__ __launch_bounds__(256) void wtrans(
    const float* __restrict__ in, unsigned short* __restrict__ outT, int K, int N)
{
  int idx = blockIdx.x * 256 + threadIdx.x;
  if (idx >= K * N) return;
  int n = idx / K, k = idx % K;
  long base = (long)blockIdx.z * K * N;
  outT[base + idx] = f2b(in[base + (long)k * N + n]);
}

__global__ __launch_bounds__(256) void wconvert(
    const float* __restrict__ in, unsigned short* __restrict__ out, int n)
{
  int idx = blockIdx.x * 256 + threadIdx.x;
  if (idx < n) out[idx] = f2b(in[idx]);
}

// outc (6,co,ci,3,3) -> (6,co,tap,ci) bf16
__global__ __launch_bounds__(256) void wpermconv(
    const float* __restrict__ in, unsigned short* __restrict__ out)
{
  int idx = blockIdx.x * 256 + threadIdx.x;   // 6*256*9*256 total, exact
  const int ci = idx & 255;
  const int t  = (idx >> 8) % 9;
  const int co = ((idx >> 8) / 9) % 256;
  const int l  = idx / (256 * 9 * 256);
  out[idx] = f2b(in[(((long)l * 256 + co) * 256 + ci) * 9 + t]);
}

// src/pos (bt,C,HW) -> output rows (bt, start+p, c); posf gets +level_embed
__global__ __launch_bounds__(256) void init_level(
    const float* __restrict__ src, const float* __restrict__ pos,
    const float* __restrict__ emb, float* __restrict__ outp,
    float* __restrict__ posf, int HW, int start)
{
  __shared__ float t1[32][33];
  __shared__ float t2[32][33];
  const int bt = blockIdx.z;
  const int p0 = blockIdx.x * 32, c0 = blockIdx.y * 32;
  const int tx = threadIdx.x, ty = threadIdx.y;
  const float* sb = src + ((long)bt * 256 + c0) * HW + p0;
  const float* pb = pos + ((long)bt * 256 + c0) * HW + p0;
#pragma unroll
  for (int j = 0; j < 4; j++) {
    int cc = ty + j * 8;
    t1[cc][tx] = sb[(long)cc * HW + tx];
    t2[cc][tx] = pb[(long)cc * HW + tx];
  }
  __syncthreads();
#pragma unroll
  for (int j = 0; j < 4; j++) {
    int pp = ty + j * 8;
    long row = (long)bt * kLQ + start + p0 + pp;
    outp[row * 256 + c0 + tx] = t1[tx][pp];
    posf[row * 256 + c0 + tx] = t2[tx][pp] + emb[c0 + tx];
  }
}

// mask (B,C,T,128,128) -> mc (BT, 16384, 256) bf16
__global__ __launch_bounds__(256) void mask_to_mc(
    const float* __restrict__ mask, unsigned short* __restrict__ mc)
{
  __shared__ float t[32][33];
  const int bt = blockIdx.z, b = bt >> 1, tt = bt & 1;
  const int p0 = blockIdx.x * 32, c0 = blockIdx.y * 32;
  const int tx = threadIdx.x, ty = threadIdx.y;
  const float* base = mask + (((long)b * 256 + c0) * 2 + tt) * 16384 + p0;
#pragma unroll
  for (int j = 0; j < 4; j++) {
    int cc = ty + j * 8;
    t[cc][tx] = base[(long)cc * 32768 + tx];
  }
  __syncthreads();
#pragma unroll
  for (int j = 0; j < 4; j++) {
    int pp = ty + j * 8;
    mc[((long)bt * 16384 + p0 + pp) * 256 + c0 + tx] = f2b(t[tx][pp]);
  }
}

__global__ __launch_bounds__(256) void copyf4(
    const float4* __restrict__ in, float4* __restrict__ out, int n)
{
  int i = blockIdx.x * blockDim.x + threadIdx.x;
  for (; i < n; i += gridDim.x * blockDim.x) out[i] = in[i];
}

// ---------------------------------------------------------------------------
extern "C" void kernel_launch(void* const* d_in, const int* in_sizes, int n_in,
                              void* d_out, int out_size, void* d_ws, size_t ws_size,
                              hipStream_t stream)
{
  const float* src[3] = {(const float*)d_in[0], (const float*)d_in[2], (const float*)d_in[4]};
  const float* pos[3] = {(const float*)d_in[1], (const float*)d_in[3], (const float*)d_in[5]};
  const float* mask_in = (const float*)d_in[6];
  const float* lemb    = (const float*)d_in[7];
  const float* off_w   = (const float*)d_in[8];
  const float* off_b   = (const float*)d_in[9];
  const float* aw_w    = (const float*)d_in[10];
  const float* aw_b    = (const float*)d_in[11];
  const float* val_w   = (const float*)d_in[12];
  const float* val_b   = (const float*)d_in[13];
  const float* out_w   = (const float*)d_in[14];
  const float* out_b   = (const float*)d_in[15];
  const float* ln1_g   = (const float*)d_in[16];
  const float* ln1_b   = (const float*)d_in[17];
  const float* ff1_w   = (const float*)d_in[18];
  const float* ff1_b   = (const float*)d_in[19];
  const float* ff2_w   = (const float*)d_in[20];
  const float* ff2_b   = (const float*)d_in[21];
  const float* ln2_g   = (const float*)d_in[22];
  const float* ln2_b   = (const float*)d_in[23];
  const float* lat_w   = (const float*)d_in[24];
  const float* lat_b   = (const float*)d_in[25];
  const float* outc_w  = (const float*)d_in[26];
  const float* outc_b  = (const float*)d_in[27];

  float* outbuf = (float*)d_out;                    // (4,5376,256)
  float* maskf  = (float*)d_out + 5505024;          // (2,256,2,128,128)

  char* wp = (char*)d_ws;
  auto alloc = [&](size_t bytes) {
    char* p = wp;
    wp += (bytes + 255) & ~(size_t)255;
    return p;
  };
  float*          posf  = (float*)alloc(5505024ull * 4);
  unsigned short* vbuf  = (unsigned short*)alloc(5505024ull * 2);
  float*          offb  = (float*)alloc(4128768ull * 4);
  float*          awb   = (float*)alloc(2064384ull * 4);
  float*          attnb = (float*)alloc(5505024ull * 4);
  float*          tmp1  = (float*)alloc(5505024ull * 4);
  unsigned short* ffh   = (unsigned short*)alloc(22020096ull * 2);
  unsigned short* mc    = (unsigned short*)alloc(16777216ull * 2);
  unsigned short* xb    = (unsigned short*)alloc(16777216ull * 2);
  unsigned short* valT  = (unsigned short*)alloc(6ull * 65536 * 2);
  unsigned short* offT  = (unsigned short*)alloc(6ull * 49152 * 2);
  unsigned short* awT   = (unsigned short*)alloc(6ull * 24576 * 2);
  unsigned short* outT  = (unsigned short*)alloc(6ull * 65536 * 2);
  unsigned short* ff1T  = (unsigned short*)alloc(6ull * 262144 * 2);
  unsigned short* ff2T  = (unsigned short*)alloc(6ull * 262144 * 2);
  unsigned short* latT  = (unsigned short*)alloc(6ull * 65536 * 2);
  unsigned short* outcT = (unsigned short*)alloc(6ull * 589824 * 2);

  // ---- weight prep (every launch; ws is re-poisoned by harness) ----
  wtrans<<<dim3(256, 1, 6), 256, 0, stream>>>(val_w, valT, 256, 256);
  wtrans<<<dim3(192, 1, 6), 256, 0, stream>>>(off_w, offT, 256, 192);
  wtrans<<<dim3(96, 1, 6),  256, 0, stream>>>(aw_w,  awT,  256, 96);
  wtrans<<<dim3(256, 1, 6), 256, 0, stream>>>(out_w, outT, 256, 256);
  wtrans<<<dim3(1024, 1, 6), 256, 0, stream>>>(ff1_w, ff1T, 256, 1024);
  wtrans<<<dim3(1024, 1, 6), 256, 0, stream>>>(ff2_w, ff2T, 1024, 256);
  wconvert<<<dim3(1536), 256, 0, stream>>>(lat_w, latT, 6 * 65536);
  wpermconv<<<dim3(13824), 256, 0, stream>>>(outc_w, outcT);

  // ---- init output / posf / mask ----
  const int hw[3] = {256, 1024, 4096};
  const int st[3] = {0, 256, 1280};
  for (int l = 0; l < 3; l++)
    init_level<<<dim3(hw[l] / 32, 8, 4), dim3(32, 8), 0, stream>>>(
        src[l], pos[l], lemb + l * 256, outbuf, posf, hw[l], st[l]);
  copyf4<<<dim3(2048), 256, 0, stream>>>(
      (const float4*)mask_in, (float4*)maskf, 4194304);

  // ---- layers ----
  for (int i = 0; i < 6; i++) {
    gemm64<1, false, false><<<dim3(336, 4), 256, 0, stream>>>(
        outbuf, nullptr, valT + (long)i * 65536, val_b + i * 256, vbuf,
        21504, 256, 256);
    gemm64<0, true, false><<<dim3(336, 3), 256, 0, stream>>>(
        outbuf, posf, offT + (long)i * 49152, off_b + i * 192, offb,
        21504, 192, 256);
    gemm64<0, true, false><<<dim3(336, 2), 256, 0, stream>>>(
        outbuf, posf, awT + (long)i * 24576, aw_b + i * 96, awb,
        21504, 96, 256);
    softmax12<<<dim3(672), 256, 0, stream>>>(awb, 172032);
    deform_sample<<<dim3(21504), 256, 0, stream>>>(offb, awb, vbuf, attnb);
    gemm64<0, false, false><<<dim3(336, 4), 256, 0, stream>>>(
        attnb, nullptr, outT + (long)i * 65536, out_b + i * 256, tmp1,
        21504, 256, 256);
    ln_residual<<<dim3(21504), 256, 0, stream>>>(
        outbuf, tmp1, ln1_g + i * 256, ln1_b + i * 256);
    gemm64<2, false, false><<<dim3(336, 16), 256, 0, stream>>>(
        outbuf, nullptr, ff1T + (long)i * 262144, ff1_b + i * 1024, ffh,
        21504, 1024, 256);
    gemm64<0, false, true><<<dim3(336, 4), 256, 0, stream>>>(
        ffh, nullptr, ff2T + (long)i * 262144, ff2_b + i * 256, tmp1,
        21504, 256, 1024);
    ln_residual<<<dim3(21504), 256, 0, stream>>>(
        outbuf, tmp1, ln2_g + i * 256, ln2_b + i * 256);
    // FPN
    mask_to_mc<<<dim3(512, 8, 4), dim3(32, 8), 0, stream>>>(maskf, mc);
    gemm64<1, false, true><<<dim3(1024, 4), 256, 0, stream>>>(
        mc, nullptr, latT + (long)i * 65536, lat_b + i * 256, xb,
        65536, 256, 256);
    resize_add<<<dim3(65536), 256, 0, stream>>>(xb, outbuf);
    conv3x3_acc<<<dim3(256, 4, 4), 256, 0, stream>>>(
        xb, outcT + (long)i * 589824, outc_b + i * 256, maskf);
  }
}

// Round 3
// 3700.027 us; speedup vs baseline: 1.0414x; 1.0414x over previous
//
#include <hip/hip_runtime.h>

#define DEV __device__ __forceinline__

using f32x4  = __attribute__((ext_vector_type(4))) float;
using bf16x8 = __attribute__((ext_vector_type(8))) short;

static constexpr int kLQ = 5376;

DEV unsigned short f2b(float f) {
  unsigned u = __builtin_bit_cast(unsigned, f);
  u = u + 0x7fffu + ((u >> 16) & 1u);
  return (unsigned short)(u >> 16);
}
DEV float b2f(unsigned short s) {
  unsigned u = ((unsigned)s) << 16;
  return __builtin_bit_cast(float, u);
}

DEV void glds16(const void* g, void* l) {
  __builtin_amdgcn_global_load_lds(
      (const __attribute__((address_space(1))) void*)g,
      (__attribute__((address_space(3))) void*)l, 16, 0, 0);
}

// ---------------------------------------------------------------------------
// gemm128: C[M][N] = A[M][K](bf16) * Bt[Npad][K](bf16, zero-padded) + bias
// 128x128 tile, BK=32, 4 waves (2x2), wave 64x64 = 4x4 16x16x32 MFMA frags.
// A,B staged via global_load_lds 16B with XOR-swizzled per-lane source:
//   16B-slot s: row = s>>2, phys col p = s&3 holds logical col p ^ ((row>>1)&3).
// EPI: 0 fp32, 1 bf16, 2 relu->bf16.
// ---------------------------------------------------------------------------
template<int EPI>
__global__ __launch_bounds__(256) void gemm128(
    const unsigned short* __restrict__ A, const unsigned short* __restrict__ Bt,
    const float* __restrict__ bias, void* __restrict__ Cp,
    int M, int N, int K)
{
  __shared__ unsigned short As[128 * 32];
  __shared__ unsigned short Bs[128 * 32];
  const int tid = threadIdx.x, lane = tid & 63, wid = tid >> 6;
  const int m0 = blockIdx.x * 128, n0 = blockIdx.y * 128;
  const int wr = wid >> 1, wc = wid & 1;
  const int l15 = lane & 15, lg = lane >> 4;

  const int s0 = wid * 64 + lane, s1 = 256 + s0;
  const int r0 = s0 >> 2, cs0 = (s0 & 3) ^ ((r0 >> 1) & 3);
  const int r1 = s1 >> 2, cs1 = (s1 & 3) ^ ((r1 >> 1) & 3);
  const unsigned short* Ag0 = A + (long)(m0 + r0) * K + cs0 * 8;
  const unsigned short* Ag1 = A + (long)(m0 + r1) * K + cs1 * 8;
  const unsigned short* Bg0 = Bt + (long)(n0 + r0) * K + cs0 * 8;
  const unsigned short* Bg1 = Bt + (long)(n0 + r1) * K + cs1 * 8;
  unsigned short* Al0 = As + (wid * 64) * 8;
  unsigned short* Al1 = As + (256 + wid * 64) * 8;
  unsigned short* Bl0 = Bs + (wid * 64) * 8;
  unsigned short* Bl1 = Bs + (256 + wid * 64) * 8;

  f32x4 acc[4][4];
#pragma unroll
  for (int i = 0; i < 4; i++)
#pragma unroll
    for (int j = 0; j < 4; j++) acc[i][j] = f32x4{0.f, 0.f, 0.f, 0.f};

  for (int k0 = 0; k0 < K; k0 += 32) {
    glds16(Ag0 + k0, Al0);
    glds16(Ag1 + k0, Al1);
    glds16(Bg0 + k0, Bl0);
    glds16(Bg1 + k0, Bl1);
    __syncthreads();
    bf16x8 a[4], b[4];
#pragma unroll
    for (int i = 0; i < 4; i++) {
      int ra = wr * 64 + i * 16 + l15;
      a[i] = *(const bf16x8*)(As + ra * 32 + (lg ^ ((ra >> 1) & 3)) * 8);
      int rb = wc * 64 + i * 16 + l15;
      b[i] = *(const bf16x8*)(Bs + rb * 32 + (lg ^ ((rb >> 1) & 3)) * 8);
    }
#pragma unroll
    for (int mi = 0; mi < 4; mi++)
#pragma unroll
      for (int nj = 0; nj < 4; nj++)
        acc[mi][nj] = __builtin_amdgcn_mfma_f32_16x16x32_bf16(
            a[mi], b[nj], acc[mi][nj], 0, 0, 0);
    __syncthreads();
  }

#pragma unroll
  for (int mi = 0; mi < 4; mi++)
#pragma unroll
    for (int nj = 0; nj < 4; nj++) {
      int col = n0 + wc * 64 + nj * 16 + l15;
      if (col >= N) continue;
      float bb = bias[col];
#pragma unroll
      for (int rr = 0; rr < 4; rr++) {
        long row = m0 + wr * 64 + mi * 16 + lg * 4 + rr;
        float v = acc[mi][nj][rr] + bb;
        if (EPI == 2) v = fmaxf(v, 0.f);
        if (EPI == 0) ((float*)Cp)[row * N + col] = v;
        else ((unsigned short*)Cp)[row * N + col] = f2b(v);
      }
    }
}

// ---------------------------------------------------------------------------
// 3x3 conv implicit GEMM, tile = 128 px (one image row) x 128 co.
// A = xb (bf16 NHWC) reg-staged w/ border predication + swizzle; B via glds.
// Accumulates relu(conv+bias) into mf (fp32 NHWC [bt][16384][256]).
// ---------------------------------------------------------------------------
__global__ __launch_bounds__(256) void conv3x3(
    const unsigned short* __restrict__ xb, const unsigned short* __restrict__ wT,
    const float* __restrict__ bias, float* __restrict__ mf)
{
  __shared__ unsigned short As[128 * 32];
  __shared__ unsigned short Bs[128 * 32];
  const int tid = threadIdx.x, lane = tid & 63, wid = tid >> 6;
  const int y = blockIdx.x, c0 = blockIdx.y * 128, bt = blockIdx.z;
  const int wr = wid >> 1, wc = wid & 1;
  const int l15 = lane & 15, lg = lane >> 4;

  const int sA0 = tid, sA1 = 256 + tid;
  const int ax0 = sA0 >> 2, acl0 = (sA0 & 3) ^ ((ax0 >> 1) & 3);
  const int ax1 = sA1 >> 2, acl1 = (sA1 & 3) ^ ((ax1 >> 1) & 3);
  const int sB0 = wid * 64 + lane, sB1 = 256 + sB0;
  const int bc0 = sB0 >> 2, bcl0 = (sB0 & 3) ^ ((bc0 >> 1) & 3);
  const int bc1 = sB1 >> 2, bcl1 = (sB1 & 3) ^ ((bc1 >> 1) & 3);
  unsigned short* Bl0 = Bs + (wid * 64) * 8;
  unsigned short* Bl1 = Bs + (256 + wid * 64) * 8;
  const unsigned short* xbb = xb + (long)bt * (16384 * 256);

  f32x4 acc[4][4];
#pragma unroll
  for (int i = 0; i < 4; i++)
#pragma unroll
    for (int j = 0; j < 4; j++) acc[i][j] = f32x4{0.f, 0.f, 0.f, 0.f};

  for (int s = 0; s < 72; s++) {
    const int t = s >> 3, ci0 = (s & 7) * 32;
    const int dy = t / 3 - 1, dx = t % 3 - 1;
    const int yy = y + dy;
    uint4 av0 = {0u, 0u, 0u, 0u}, av1 = {0u, 0u, 0u, 0u};
    const int xx0 = ax0 + dx, xx1 = ax1 + dx;
    if ((unsigned)yy < 128u) {
      if ((unsigned)xx0 < 128u)
        av0 = *(const uint4*)(xbb + ((long)(yy * 128 + xx0)) * 256 + ci0 + acl0 * 8);
      if ((unsigned)xx1 < 128u)
        av1 = *(const uint4*)(xbb + ((long)(yy * 128 + xx1)) * 256 + ci0 + acl1 * 8);
    }
    *(uint4*)(As + sA0 * 8) = av0;
    *(uint4*)(As + sA1 * 8) = av1;
    glds16(wT + ((long)(c0 + bc0) * 9 + t) * 256 + ci0 + bcl0 * 8, Bl0);
    glds16(wT + ((long)(c0 + bc1) * 9 + t) * 256 + ci0 + bcl1 * 8, Bl1);
    __syncthreads();
    bf16x8 a[4], b[4];
#pragma unroll
    for (int i = 0; i < 4; i++) {
      int ra = wr * 64 + i * 16 + l15;
      a[i] = *(const bf16x8*)(As + ra * 32 + (lg ^ ((ra >> 1) & 3)) * 8);
      int rb = wc * 64 + i * 16 + l15;
      b[i] = *(const bf16x8*)(Bs + rb * 32 + (lg ^ ((rb >> 1) & 3)) * 8);
    }
#pragma unroll
    for (int mi = 0; mi < 4; mi++)
#pragma unroll
      for (int nj = 0; nj < 4; nj++)
        acc[mi][nj] = __builtin_amdgcn_mfma_f32_16x16x32_bf16(
            a[mi], b[nj], acc[mi][nj], 0, 0, 0);
    __syncthreads();
  }

#pragma unroll
  for (int mi = 0; mi < 4; mi++)
#pragma unroll
    for (int nj = 0; nj < 4; nj++) {
      int co = c0 + wc * 64 + nj * 16 + l15;
      float bb = bias[co];
#pragma unroll
      for (int rr = 0; rr < 4; rr++) {
        int x = wr * 64 + mi * 16 + lg * 4 + rr;
        long idx = ((long)bt * 16384 + y * 128 + x) * 256 + co;
        mf[idx] += fmaxf(acc[mi][nj][rr] + bb, 0.f);
      }
    }
}

// ---------------------------------------------------------------------------
// Deformable-attention bilinear sampling -> bf16 attn.
// ---------------------------------------------------------------------------
__global__ __launch_bounds__(256) void deform_sample(
    const float* __restrict__ offp, const float* __restrict__ awp,
    const unsigned short* __restrict__ vp, unsigned short* __restrict__ attn)
{
  const int m = blockIdx.x;
  const int bt = m / kLQ, q = m % kLQ;
  const int tid = threadIdx.x;
  const int h = tid >> 5;
  int pq, Wq;
  if (q < 256)       { pq = q;        Wq = 16; }
  else if (q < 1280) { pq = q - 256;  Wq = 32; }
  else               { pq = q - 1280; Wq = 64; }
  const float refx = ((pq % Wq) + 0.5f) / Wq;
  const float refy = ((pq / Wq) + 0.5f) / Wq;
  const int starts[3] = {0, 256, 1280};
  const int dims[3]   = {16, 32, 64};
  const float* offr = offp + (long)m * 192 + h * 24;
  const float* awr  = awp  + (long)m * 96  + h * 12;
  const unsigned short* vb = vp + ((long)bt * kLQ) * 256 + tid;
  float acc = 0.f;
#pragma unroll
  for (int l = 0; l < 3; l++) {
    const int Wl = dims[l];
    const float inv = 1.f / (float)Wl;
    const int st = starts[l];
#pragma unroll
    for (int p = 0; p < 4; p++) {
      float ox = offr[l * 8 + p * 2], oy = offr[l * 8 + p * 2 + 1];
      float a  = awr[l * 4 + p];
      float fxp = (refx + ox * inv) * Wl - 0.5f;
      float fyp = (refy + oy * inv) * Wl - 0.5f;
      float x0f = floorf(fxp), y0f = floorf(fyp);
      int x0 = (int)x0f, y0 = (int)y0f;
      float fx = fxp - x0f, fy = fyp - y0f;
      float sacc = 0.f;
#pragma unroll
      for (int cy = 0; cy < 2; cy++)
#pragma unroll
        for (int cx = 0; cx < 2; cx++) {
          int ix = x0 + cx, iy = y0 + cy;
          if ((unsigned)ix < (unsigned)Wl && (unsigned)iy < (unsigned)Wl) {
            float w = (cx ? fx : 1.f - fx) * (cy ? fy : 1.f - fy);
            sacc += w * b2f(vb[((long)(st + iy * Wl + ix)) * 256]);
          }
        }
      acc += a * sacc;
    }
  }
  attn[(long)m * 256 + tid] = f2b(acc);
}

__global__ __launch_bounds__(256) void softmax12(float* __restrict__ aw, int total)
{
  int i = blockIdx.x * 256 + threadIdx.x;
  if (i >= total) return;
  float* p = aw + (long)i * 12;
  float mx = p[0];
#pragma unroll
  for (int j = 1; j < 12; j++) mx = fmaxf(mx, p[j]);
  float s = 0.f;
#pragma unroll
  for (int j = 0; j < 12; j++) { float e = __expf(p[j] - mx); p[j] = e; s += e; }
  float invs = 1.f / s;
#pragma unroll
  for (int j = 0; j < 12; j++) p[j] *= invs;
}

// out = LN(out + delta); writes fp32 out and bf16 ob
__global__ __launch_bounds__(256) void ln_residual(
    float* __restrict__ out, const float* __restrict__ delta,
    const float* __restrict__ g, const float* __restrict__ b,
    unsigned short* __restrict__ ob)
{
  const long m = blockIdx.x;
  const int c = threadIdx.x;
  float x = out[m * 256 + c] + delta[m * 256 + c];
  __shared__ float red[4], red2[4];
  float s = x;
#pragma unroll
  for (int o = 32; o > 0; o >>= 1) s += __shfl_down(s, o);
  if ((c & 63) == 0) red[c >> 6] = s;
  __syncthreads();
  float mean = (red[0] + red[1] + red[2] + red[3]) * (1.f / 256.f);
  float dx = x - mean;
  float s2 = dx * dx;
#pragma unroll
  for (int o = 32; o > 0; o >>= 1) s2 += __shfl_down(s2, o);
  if ((c & 63) == 0) red2[c >> 6] = s2;
  __syncthreads();
  float var = (red2[0] + red2[1] + red2[2] + red2[3]) * (1.f / 256.f);
  float r = dx * rsqrtf(var + 1e-5f) * g[c] + b[c];
  out[m * 256 + c] = r;
  ob[m * 256 + c] = f2b(r);
}

// qb = bf16(output + posf)
__global__ __launch_bounds__(256) void make_qb(
    const float* __restrict__ o, const float* __restrict__ p,
    unsigned short* __restrict__ qb)
{
  int i = blockIdx.x * 256 + threadIdx.x;   // 1376256 float4 groups exact
  float4 a = ((const float4*)o)[i], b = ((const float4*)p)[i];
  ushort4 r;
  r.x = f2b(a.x + b.x); r.y = f2b(a.y + b.y);
  r.z = f2b(a.z + b.z); r.w = f2b(a.w + b.w);
  ((ushort4*)qb)[i] = r;
}

// fp32 -> bf16 elementwise (mf_hwc -> mc)
__global__ __launch_bounds__(256) void f32_to_bf16(
    const float* __restrict__ in, unsigned short* __restrict__ out, int n4)
{
  int i = blockIdx.x * 256 + threadIdx.x;
  if (i >= n4) return;
  float4 a = ((const float4*)in)[i];
  ushort4 r;
  r.x = f2b(a.x); r.y = f2b(a.y); r.z = f2b(a.z); r.w = f2b(a.w);
  ((ushort4*)out)[i] = r;
}

// xb[bt,y,x,c] += bilinear_resize(output[:,1280:] as 64x64)(y,x,c)
__global__ __launch_bounds__(256) void resize_add(
    unsigned short* __restrict__ xb, const float* __restrict__ out)
{
  const int pix = blockIdx.x;
  const int bt = pix >> 14;
  const int y = (pix >> 7) & 127, x = pix & 127;
  const int c = threadIdx.x;
  float sy = y * 0.5f - 0.25f, sx = x * 0.5f - 0.25f;
  float y0f = floorf(sy), x0f = floorf(sx);
  float fy = sy - y0f, fx = sx - x0f;
  int y0 = min(63, max(0, (int)y0f)), y1 = min(63, max(0, (int)y0f + 1));
  int x0 = min(63, max(0, (int)x0f)), x1 = min(63, max(0, (int)x0f + 1));
  const float* base = out + ((long)bt * kLQ + 1280) * 256 + c;
  float v00 = base[(long)(y0 * 64 + x0) * 256];
  float v01 = base[(long)(y0 * 64 + x1) * 256];
  float v10 = base[(long)(y1 * 64 + x0) * 256];
  float v11 = base[(long)(y1 * 64 + x1) * 256];
  float v = (1.f - fy) * ((1.f - fx) * v00 + fx * v01)
          + fy * ((1.f - fx) * v10 + fx * v11);
  long idx = (long)pix * 256 + c;
  xb[idx] = f2b(b2f(xb[idx]) + v);
}

// weight transpose+convert+pad: outT[l][n][k] = n<N ? bf16(in[l][k][n]) : 0
__global__ __launch_bounds__(256) void wtrans_pad(
    const float* __restrict__ in, unsigned short* __restrict__ outT,
    int K, int N, int Npad)
{
  int idx = blockIdx.x * 256 + threadIdx.x;
  if (idx >= Npad * K) return;
  int n = idx / K, k = idx % K;
  unsigned short v = 0;
  if (n < N) v = f2b(in[(long)blockIdx.z * K * N + (long)k * N + n]);
  outT[(long)blockIdx.z * Npad * K + idx] = v;
}

__global__ __launch_bounds__(256) void wconvert(
    const float* __restrict__ in, unsigned short* __restrict__ out, int n)
{
  int idx = blockIdx.x * 256 + threadIdx.x;
  if (idx < n) out[idx] = f2b(in[idx]);
}

// outc (6,co,ci,3,3) -> (6,co,tap,ci) bf16
__global__ __launch_bounds__(256) void wpermconv(
    const float* __restrict__ in, unsigned short* __restrict__ out)
{
  int idx = blockIdx.x * 256 + threadIdx.x;
  const int ci = idx & 255;
  const int t  = (idx >> 8) % 9;
  const int co = ((idx >> 8) / 9) % 256;
  const int l  = idx / (256 * 9 * 256);
  out[idx] = f2b(in[(((long)l * 256 + co) * 256 + ci) * 9 + t]);
}

// src/pos (bt,C,HW) -> output rows fp32 + ob bf16; posf = pos + level_embed
__global__ __launch_bounds__(256) void init_level(
    const float* __restrict__ src, const float* __restrict__ pos,
    const float* __restrict__ emb, float* __restrict__ outp,
    float* __restrict__ posf, unsigned short* __restrict__ ob,
    int HW, int start)
{
  __shared__ float t1[32][33];
  __shared__ float t2[32][33];
  const int bt = blockIdx.z;
  const int p0 = blockIdx.x * 32, c0 = blockIdx.y * 32;
  const int tx = threadIdx.x, ty = threadIdx.y;
  const float* sb = src + ((long)bt * 256 + c0) * HW + p0;
  const float* pb = pos + ((long)bt * 256 + c0) * HW + p0;
#pragma unroll
  for (int j = 0; j < 4; j++) {
    int cc = ty + j * 8;
    t1[cc][tx] = sb[(long)cc * HW + tx];
    t2[cc][tx] = pb[(long)cc * HW + tx];
  }
  __syncthreads();
#pragma unroll
  for (int j = 0; j < 4; j++) {
    int pp = ty + j * 8;
    long row = (long)bt * kLQ + start + p0 + pp;
    float v = t1[tx][pp];
    outp[row * 256 + c0 + tx] = v;
    ob[row * 256 + c0 + tx] = f2b(v);
    posf[row * 256 + c0 + tx] = t2[tx][pp] + emb[c0 + tx];
  }
}

// mask_in (b,c,t,128,128) -> mf_hwc [bt][16384][256] fp32
__global__ __launch_bounds__(256) void init_mask(
    const float* __restrict__ in, float* __restrict__ mf)
{
  __shared__ float t[32][33];
  const int bt = blockIdx.z, b = bt >> 1, tt = bt & 1;
  const int p0 = blockIdx.x * 32, c0 = blockIdx.y * 32;
  const int tx = threadIdx.x, ty = threadIdx.y;
  const float* base = in + (((long)b * 256 + c0) * 2 + tt) * 16384 + p0;
#pragma unroll
  for (int j = 0; j < 4; j++) {
    int cc = ty + j * 8;
    t[cc][tx] = base[(long)cc * 32768 + tx];
  }
  __syncthreads();
#pragma unroll
  for (int j = 0; j < 4; j++) {
    int pp = ty + j * 8;
    mf[((long)bt * 16384 + p0 + pp) * 256 + c0 + tx] = t[tx][pp];
  }
}

// mf_hwc -> d_out mask region (b,c,t,128,128) fp32
__global__ __launch_bounds__(256) void hwc_to_out(
    const float* __restrict__ mf, float* __restrict__ outm)
{
  __shared__ float t[32][33];
  const int bt = blockIdx.z, b = bt >> 1, tt = bt & 1;
  const int p0 = blockIdx.x * 32, c0 = blockIdx.y * 32;
  const int tx = threadIdx.x, ty = threadIdx.y;
#pragma unroll
  for (int j = 0; j < 4; j++) {
    int pp = ty + j * 8;
    t[pp][tx] = mf[((long)bt * 16384 + p0 + pp) * 256 + c0 + tx];
  }
  __syncthreads();
#pragma unroll
  for (int j = 0; j < 4; j++) {
    int cc = ty + j * 8;
    outm[(((long)b * 256 + c0 + cc) * 2 + tt) * 16384 + p0 + tx] = t[tx][cc];
  }
}

// ---------------------------------------------------------------------------
extern "C" void kernel_launch(void* const* d_in, const int* in_sizes, int n_in,
                              void* d_out, int out_size, void* d_ws, size_t ws_size,
                              hipStream_t stream)
{
  const float* src[3] = {(const float*)d_in[0], (const float*)d_in[2], (const float*)d_in[4]};
  const float* pos[3] = {(const float*)d_in[1], (const float*)d_in[3], (const float*)d_in[5]};
  const float* mask_in = (const float*)d_in[6];
  const float* lemb    = (const float*)d_in[7];
  const float* off_w   = (const float*)d_in[8];
  const float* off_b   = (const float*)d_in[9];
  const float* aw_w    = (const float*)d_in[10];
  const float* aw_b    = (const float*)d_in[11];
  const float* val_w   = (const float*)d_in[12];
  const float* val_b   = (const float*)d_in[13];
  const float* out_w   = (const float*)d_in[14];
  const float* out_b   = (const float*)d_in[15];
  const float* ln1_g   = (const float*)d_in[16];
  const float* ln1_b   = (const float*)d_in[17];
  const float* ff1_w   = (const float*)d_in[18];
  const float* ff1_b   = (const float*)d_in[19];
  const float* ff2_w   = (const float*)d_in[20];
  const float* ff2_b   = (const float*)d_in[21];
  const float* ln2_g   = (const float*)d_in[22];
  const float* ln2_b   = (const float*)d_in[23];
  const float* lat_w   = (const float*)d_in[24];
  const float* lat_b   = (const float*)d_in[25];
  const float* outc_w  = (const float*)d_in[26];
  const float* outc_b  = (const float*)d_in[27];

  float* outbuf = (float*)d_out;                    // (4,5376,256)
  float* maskf  = (float*)d_out + 5505024;          // (2,256,2,128,128)

  char* wp = (char*)d_ws;
  auto alloc = [&](size_t bytes) {
    char* p = wp;
    wp += (bytes + 255) & ~(size_t)255;
    return p;
  };
  float*          posf  = (float*)alloc(5505024ull * 4);
  unsigned short* qb    = (unsigned short*)alloc(5505024ull * 2);
  unsigned short* ob    = (unsigned short*)alloc(5505024ull * 2);
  unsigned short* vbuf  = (unsigned short*)alloc(5505024ull * 2);
  float*          offb  = (float*)alloc(4128768ull * 4);
  float*          awb   = (float*)alloc(2064384ull * 4);
  unsigned short* attnb = (unsigned short*)alloc(5505024ull * 2);
  float*          tmp1  = (float*)alloc(5505024ull * 4);
  unsigned short* ffh   = (unsigned short*)alloc(22020096ull * 2);
  unsigned short* mc    = (unsigned short*)alloc(16777216ull * 2);
  unsigned short* xb    = (unsigned short*)alloc(16777216ull * 2);
  float*          mfh   = (float*)alloc(16777216ull * 4);
  unsigned short* valT  = (unsigned short*)alloc(6ull * 65536 * 2);
  unsigned short* offT  = (unsigned short*)alloc(6ull * 65536 * 2);   // 256x256 padded
  unsigned short* awT   = (unsigned short*)alloc(6ull * 32768 * 2);   // 128x256 padded
  unsigned short* outT  = (unsigned short*)alloc(6ull * 65536 * 2);
  unsigned short* ff1T  = (unsigned short*)alloc(6ull * 262144 * 2);
  unsigned short* ff2T  = (unsigned short*)alloc(6ull * 262144 * 2);
  unsigned short* latT  = (unsigned short*)alloc(6ull * 65536 * 2);
  unsigned short* outcT = (unsigned short*)alloc(6ull * 589824 * 2);

  // ---- weight prep ----
  wtrans_pad<<<dim3(256, 1, 6), 256, 0, stream>>>(val_w, valT, 256, 256, 256);
  wtrans_pad<<<dim3(256, 1, 6), 256, 0, stream>>>(off_w, offT, 256, 192, 256);
  wtrans_pad<<<dim3(128, 1, 6), 256, 0, stream>>>(aw_w,  awT,  256, 96, 128);
  wtrans_pad<<<dim3(256, 1, 6), 256, 0, stream>>>(out_w, outT, 256, 256, 256);
  wtrans_pad<<<dim3(1024, 1, 6), 256, 0, stream>>>(ff1_w, ff1T, 256, 1024, 1024);
  wtrans_pad<<<dim3(1024, 1, 6), 256, 0, stream>>>(ff2_w, ff2T, 1024, 256, 256);
  wconvert<<<dim3(1536), 256, 0, stream>>>(lat_w, latT, 6 * 65536);
  wpermconv<<<dim3(13824), 256, 0, stream>>>(outc_w, outcT);

  // ---- init ----
  const int hw[3] = {256, 1024, 4096};
  const int st[3] = {0, 256, 1280};
  for (int l = 0; l < 3; l++)
    init_level<<<dim3(hw[l] / 32, 8, 4), dim3(32, 8), 0, stream>>>(
        src[l], pos[l], lemb + l * 256, outbuf, posf, ob, hw[l], st[l]);
  init_mask<<<dim3(512, 8, 4), dim3(32, 8), 0, stream>>>(mask_in, mfh);

  // ---- layers ----
  for (int i = 0; i < 6; i++) {
    make_qb<<<dim3(5376), 256, 0, stream>>>(outbuf, posf, qb);
    gemm128<1><<<dim3(168, 2), 256, 0, stream>>>(
        ob, valT + (long)i * 65536, val_b + i * 256, vbuf, 21504, 256, 256);
    gemm128<0><<<dim3(168, 2), 256, 0, stream>>>(
        qb, offT + (long)i * 65536, off_b + i * 192, offb, 21504, 192, 256);
    gemm128<0><<<dim3(168, 1), 256, 0, stream>>>(
        qb, awT + (long)i * 32768, aw_b + i * 96, awb, 21504, 96, 256);
    softmax12<<<dim3(672), 256, 0, stream>>>(awb, 172032);
    deform_sample<<<dim3(21504), 256, 0, stream>>>(offb, awb, vbuf, attnb);
    gemm128<0><<<dim3(168, 2), 256, 0, stream>>>(
        attnb, outT + (long)i * 65536, out_b + i * 256, tmp1, 21504, 256, 256);
    ln_residual<<<dim3(21504), 256, 0, stream>>>(
        outbuf, tmp1, ln1_g + i * 256, ln1_b + i * 256, ob);
    gemm128<2><<<dim3(168, 8), 256, 0, stream>>>(
        ob, ff1T + (long)i * 262144, ff1_b + i * 1024, ffh, 21504, 1024, 256);
    gemm128<0><<<dim3(168, 2), 256, 0, stream>>>(
        ffh, ff2T + (long)i * 262144, ff2_b + i * 256, tmp1, 21504, 256, 1024);
    ln_residual<<<dim3(21504), 256, 0, stream>>>(
        outbuf, tmp1, ln2_g + i * 256, ln2_b + i * 256, ob);
    // FPN
    f32_to_bf16<<<dim3(16384), 256, 0, stream>>>(mfh, mc, 4194304);
    gemm128<1><<<dim3(512, 2), 256, 0, stream>>>(
        mc, latT + (long)i * 65536, lat_b + i * 256, xb, 65536, 256, 256);
    resize_add<<<dim3(65536), 256, 0, stream>>>(xb, outbuf);
    conv3x3<<<dim3(128, 2, 4), 256, 0, stream>>>(
        xb, outcT + (long)i * 589824, outc_b + i * 256, mfh);
  }
  hwc_to_out<<<dim3(512, 8, 4), dim3(32, 8), 0, stream>>>(mfh, maskf);
}

// Round 4
// 3068.935 us; speedup vs baseline: 1.2556x; 1.2056x over previous
//
#include <hip/hip_runtime.h>

#define DEV __device__ __forceinline__

using f32x4  = __attribute__((ext_vector_type(4))) float;
using bf16x8 = __attribute__((ext_vector_type(8))) short;

static constexpr int kLQ = 5376;

DEV unsigned short f2b(float f) {
  unsigned u = __builtin_bit_cast(unsigned, f);
  u = u + 0x7fffu + ((u >> 16) & 1u);
  return (unsigned short)(u >> 16);
}
DEV float b2f(unsigned short s) {
  unsigned u = ((unsigned)s) << 16;
  return __builtin_bit_cast(float, u);
}

DEV void glds16(const void* g, void* l) {
  __builtin_amdgcn_global_load_lds(
      (const __attribute__((address_space(1))) void*)g,
      (__attribute__((address_space(3))) void*)l, 16, 0, 0);
}

// ---------------------------------------------------------------------------
// gemm128: C[M][N] = A[M][K](bf16) * Bt[Npad][K](bf16, zero-padded) + bias
// 128x128 tile, BK=32, 4 waves (2x2), wave 64x64 = 4x4 16x16x32 MFMA frags.
// A,B via global_load_lds 16B, XOR-swizzled per-lane source (rule #21).
// EPI: 0 fp32, 1 bf16, 2 relu->bf16, 3 bf16 + fused bilinear-resize add.
// ---------------------------------------------------------------------------
template<int EPI>
__global__ __launch_bounds__(256) void gemm128(
    const unsigned short* __restrict__ A, const unsigned short* __restrict__ Bt,
    const float* __restrict__ bias, void* __restrict__ Cp,
    int M, int N, int K, const float* __restrict__ rsrc)
{
  __shared__ unsigned short As[128 * 32];
  __shared__ unsigned short Bs[128 * 32];
  const int tid = threadIdx.x, lane = tid & 63, wid = tid >> 6;
  const int m0 = blockIdx.x * 128, n0 = blockIdx.y * 128;
  const int wr = wid >> 1, wc = wid & 1;
  const int l15 = lane & 15, lg = lane >> 4;

  const int s0 = wid * 64 + lane, s1 = 256 + s0;
  const int r0 = s0 >> 2, cs0 = (s0 & 3) ^ ((r0 >> 1) & 3);
  const int r1 = s1 >> 2, cs1 = (s1 & 3) ^ ((r1 >> 1) & 3);
  const unsigned short* Ag0 = A + (long)(m0 + r0) * K + cs0 * 8;
  const unsigned short* Ag1 = A + (long)(m0 + r1) * K + cs1 * 8;
  const unsigned short* Bg0 = Bt + (long)(n0 + r0) * K + cs0 * 8;
  const unsigned short* Bg1 = Bt + (long)(n0 + r1) * K + cs1 * 8;
  unsigned short* Al0 = As + (wid * 64) * 8;
  unsigned short* Al1 = As + (256 + wid * 64) * 8;
  unsigned short* Bl0 = Bs + (wid * 64) * 8;
  unsigned short* Bl1 = Bs + (256 + wid * 64) * 8;

  f32x4 acc[4][4];
#pragma unroll
  for (int i = 0; i < 4; i++)
#pragma unroll
    for (int j = 0; j < 4; j++) acc[i][j] = f32x4{0.f, 0.f, 0.f, 0.f};

  for (int k0 = 0; k0 < K; k0 += 32) {
    glds16(Ag0 + k0, Al0);
    glds16(Ag1 + k0, Al1);
    glds16(Bg0 + k0, Bl0);
    glds16(Bg1 + k0, Bl1);
    __syncthreads();
    bf16x8 a[4], b[4];
#pragma unroll
    for (int i = 0; i < 4; i++) {
      int ra = wr * 64 + i * 16 + l15;
      a[i] = *(const bf16x8*)(As + ra * 32 + (lg ^ ((ra >> 1) & 3)) * 8);
      int rb = wc * 64 + i * 16 + l15;
      b[i] = *(const bf16x8*)(Bs + rb * 32 + (lg ^ ((rb >> 1) & 3)) * 8);
    }
#pragma unroll
    for (int mi = 0; mi < 4; mi++)
#pragma unroll
      for (int nj = 0; nj < 4; nj++)
        acc[mi][nj] = __builtin_amdgcn_mfma_f32_16x16x32_bf16(
            a[mi], b[nj], acc[mi][nj], 0, 0, 0);
    __syncthreads();
  }

  // EPI==3: block covers one image row (bt, y) of the 128x128 output.
  int ry0 = 0, ry1 = 0;
  float rfy = 0.f;
  const float* rb0 = nullptr;
  if (EPI == 3) {
    const int bt = m0 >> 14, y = (m0 & 16383) >> 7;
    float sy = y * 0.5f - 0.25f;
    float y0f = floorf(sy);
    rfy = sy - y0f;
    ry0 = min(63, max(0, (int)y0f));
    ry1 = min(63, max(0, (int)y0f + 1));
    rb0 = rsrc + ((long)bt * kLQ + 1280) * 256;
  }

#pragma unroll
  for (int mi = 0; mi < 4; mi++)
#pragma unroll
    for (int nj = 0; nj < 4; nj++) {
      int col = n0 + wc * 64 + nj * 16 + l15;
      if (col >= N) continue;
      float bb = bias[col];
#pragma unroll
      for (int rr = 0; rr < 4; rr++) {
        long row = m0 + wr * 64 + mi * 16 + lg * 4 + rr;
        float v = acc[mi][nj][rr] + bb;
        if (EPI == 2) v = fmaxf(v, 0.f);
        if (EPI == 3) {
          int x = wr * 64 + mi * 16 + lg * 4 + rr;
          float sx = x * 0.5f - 0.25f;
          float x0f = floorf(sx);
          float fx = sx - x0f;
          int x0 = min(63, max(0, (int)x0f)), x1 = min(63, max(0, (int)x0f + 1));
          float v00 = rb0[(long)(ry0 * 64 + x0) * 256 + col];
          float v01 = rb0[(long)(ry0 * 64 + x1) * 256 + col];
          float v10 = rb0[(long)(ry1 * 64 + x0) * 256 + col];
          float v11 = rb0[(long)(ry1 * 64 + x1) * 256 + col];
          v += (1.f - rfy) * ((1.f - fx) * v00 + fx * v01)
             + rfy * ((1.f - fx) * v10 + fx * v11);
        }
        if (EPI == 0) ((float*)Cp)[row * N + col] = v;
        else ((unsigned short*)Cp)[row * N + col] = f2b(v);
      }
    }
}

// ---------------------------------------------------------------------------
// 3x3 conv implicit GEMM, tile = 128 px (one image row) x 128 co.
// Epilogue: mf += relu(conv+bias) (fp32 NHWC) and mc = bf16(mf).
// ---------------------------------------------------------------------------
__global__ __launch_bounds__(256) void conv3x3(
    const unsigned short* __restrict__ xb, const unsigned short* __restrict__ wT,
    const float* __restrict__ bias, float* __restrict__ mf,
    unsigned short* __restrict__ mc)
{
  __shared__ unsigned short As[128 * 32];
  __shared__ unsigned short Bs[128 * 32];
  const int tid = threadIdx.x, lane = tid & 63, wid = tid >> 6;
  const int y = blockIdx.x, c0 = blockIdx.y * 128, bt = blockIdx.z;
  const int wr = wid >> 1, wc = wid & 1;
  const int l15 = lane & 15, lg = lane >> 4;

  const int sA0 = tid, sA1 = 256 + tid;
  const int ax0 = sA0 >> 2, acl0 = (sA0 & 3) ^ ((ax0 >> 1) & 3);
  const int ax1 = sA1 >> 2, acl1 = (sA1 & 3) ^ ((ax1 >> 1) & 3);
  const int sB0 = wid * 64 + lane, sB1 = 256 + sB0;
  const int bc0 = sB0 >> 2, bcl0 = (sB0 & 3) ^ ((bc0 >> 1) & 3);
  const int bc1 = sB1 >> 2, bcl1 = (sB1 & 3) ^ ((bc1 >> 1) & 3);
  unsigned short* Bl0 = Bs + (wid * 64) * 8;
  unsigned short* Bl1 = Bs + (256 + wid * 64) * 8;
  const unsigned short* xbb = xb + (long)bt * (16384 * 256);

  f32x4 acc[4][4];
#pragma unroll
  for (int i = 0; i < 4; i++)
#pragma unroll
    for (int j = 0; j < 4; j++) acc[i][j] = f32x4{0.f, 0.f, 0.f, 0.f};

  for (int s = 0; s < 72; s++) {
    const int t = s >> 3, ci0 = (s & 7) * 32;
    const int dy = t / 3 - 1, dx = t % 3 - 1;
    const int yy = y + dy;
    uint4 av0 = {0u, 0u, 0u, 0u}, av1 = {0u, 0u, 0u, 0u};
    const int xx0 = ax0 + dx, xx1 = ax1 + dx;
    if ((unsigned)yy < 128u) {
      if ((unsigned)xx0 < 128u)
        av0 = *(const uint4*)(xbb + ((long)(yy * 128 + xx0)) * 256 + ci0 + acl0 * 8);
      if ((unsigned)xx1 < 128u)
        av1 = *(const uint4*)(xbb + ((long)(yy * 128 + xx1)) * 256 + ci0 + acl1 * 8);
    }
    *(uint4*)(As + sA0 * 8) = av0;
    *(uint4*)(As + sA1 * 8) = av1;
    glds16(wT + ((long)(c0 + bc0) * 9 + t) * 256 + ci0 + bcl0 * 8, Bl0);
    glds16(wT + ((long)(c0 + bc1) * 9 + t) * 256 + ci0 + bcl1 * 8, Bl1);
    __syncthreads();
    bf16x8 a[4], b[4];
#pragma unroll
    for (int i = 0; i < 4; i++) {
      int ra = wr * 64 + i * 16 + l15;
      a[i] = *(const bf16x8*)(As + ra * 32 + (lg ^ ((ra >> 1) & 3)) * 8);
      int rb = wc * 64 + i * 16 + l15;
      b[i] = *(const bf16x8*)(Bs + rb * 32 + (lg ^ ((rb >> 1) & 3)) * 8);
    }
#pragma unroll
    for (int mi = 0; mi < 4; mi++)
#pragma unroll
      for (int nj = 0; nj < 4; nj++)
        acc[mi][nj] = __builtin_amdgcn_mfma_f32_16x16x32_bf16(
            a[mi], b[nj], acc[mi][nj], 0, 0, 0);
    __syncthreads();
  }

#pragma unroll
  for (int mi = 0; mi < 4; mi++)
#pragma unroll
    for (int nj = 0; nj < 4; nj++) {
      int co = c0 + wc * 64 + nj * 16 + l15;
      float bb = bias[co];
#pragma unroll
      for (int rr = 0; rr < 4; rr++) {
        int x = wr * 64 + mi * 16 + lg * 4 + rr;
        long idx = ((long)bt * 16384 + y * 128 + x) * 256 + co;
        float v = mf[idx] + fmaxf(acc[mi][nj][rr] + bb, 0.f);
        mf[idx] = v;
        mc[idx] = f2b(v);
      }
    }
}

// ---------------------------------------------------------------------------
// Deformable-attention sampling + fused softmax.
// 64 threads per query: h = t>>3 (8 heads), d4 = t&7 (4 channels each).
// Each thread: ushort4 channel loads, float4 bilinear math.
// ---------------------------------------------------------------------------
__global__ __launch_bounds__(256) void deform_sample(
    const float* __restrict__ offp, const float* __restrict__ awlog,
    const unsigned short* __restrict__ vp, unsigned short* __restrict__ attn)
{
  const int m = blockIdx.x * 4 + (threadIdx.x >> 6);
  const int t = threadIdx.x & 63;
  const int h = t >> 3, d4 = t & 7;
  const int bt = m / kLQ, q = m % kLQ;
  int pq, Wq;
  if (q < 256)       { pq = q;        Wq = 16; }
  else if (q < 1280) { pq = q - 256;  Wq = 32; }
  else               { pq = q - 1280; Wq = 64; }
  const float refx = ((pq % Wq) + 0.5f) / Wq;
  const float refy = ((pq / Wq) + 0.5f) / Wq;
  const int starts[3] = {0, 256, 1280};
  const int dims[3]   = {16, 32, 64};

  // offsets: 24 floats = 6 float4; logits: 12 floats = 3 float4
  const float4* offr = (const float4*)(offp + (long)m * 192 + h * 24);
  const float4* awr  = (const float4*)(awlog + (long)m * 96 + h * 12);
  float off[24], aw[12];
#pragma unroll
  for (int j = 0; j < 6; j++) {
    float4 v = offr[j];
    off[j * 4] = v.x; off[j * 4 + 1] = v.y; off[j * 4 + 2] = v.z; off[j * 4 + 3] = v.w;
  }
#pragma unroll
  for (int j = 0; j < 3; j++) {
    float4 v = awr[j];
    aw[j * 4] = v.x; aw[j * 4 + 1] = v.y; aw[j * 4 + 2] = v.z; aw[j * 4 + 3] = v.w;
  }
  // softmax over 12
  float mx = aw[0];
#pragma unroll
  for (int j = 1; j < 12; j++) mx = fmaxf(mx, aw[j]);
  float ssum = 0.f;
#pragma unroll
  for (int j = 0; j < 12; j++) { float e = __expf(aw[j] - mx); aw[j] = e; ssum += e; }
  float inv = 1.f / ssum;

  const unsigned short* vb = vp + ((long)bt * kLQ) * 256 + h * 32 + d4 * 4;
  float ax = 0.f, ay = 0.f, az = 0.f, aww = 0.f;
#pragma unroll
  for (int l = 0; l < 3; l++) {
    const int Wl = dims[l];
    const float winv = 1.f / (float)Wl;
    const int st = starts[l];
#pragma unroll
    for (int p = 0; p < 4; p++) {
      float ox = off[l * 8 + p * 2], oy = off[l * 8 + p * 2 + 1];
      float a  = aw[l * 4 + p] * inv;
      float fxp = (refx + ox * winv) * Wl - 0.5f;
      float fyp = (refy + oy * winv) * Wl - 0.5f;
      float x0f = floorf(fxp), y0f = floorf(fyp);
      int x0 = (int)x0f, y0 = (int)y0f;
      float fx = fxp - x0f, fy = fyp - y0f;
      float sx = 0.f, sy = 0.f, sz = 0.f, sw = 0.f;
#pragma unroll
      for (int cy = 0; cy < 2; cy++)
#pragma unroll
        for (int cx = 0; cx < 2; cx++) {
          int ix = x0 + cx, iy = y0 + cy;
          if ((unsigned)ix < (unsigned)Wl && (unsigned)iy < (unsigned)Wl) {
            float w = (cx ? fx : 1.f - fx) * (cy ? fy : 1.f - fy);
            ushort4 u = *(const ushort4*)(vb + (long)(st + iy * Wl + ix) * 256);
            sx += w * b2f(u.x); sy += w * b2f(u.y);
            sz += w * b2f(u.z); sw += w * b2f(u.w);
          }
        }
      ax += a * sx; ay += a * sy; az += a * sz; aww += a * sw;
    }
  }
  ushort4 r;
  r.x = f2b(ax); r.y = f2b(ay); r.z = f2b(az); r.w = f2b(aww);
  *(ushort4*)(attn + (long)m * 256 + h * 32 + d4 * 4) = r;
}

// ---------------------------------------------------------------------------
// LN: one wave per row, float4 per lane, shfl_xor butterfly (no LDS).
// out = LN(out + delta) * g + b -> fp32 out, bf16 ob; QB: qb = bf16(r + posf).
// ---------------------------------------------------------------------------
template<bool QB>
__global__ __launch_bounds__(256) void ln_row(
    float* __restrict__ out, const float* __restrict__ delta,
    const float* __restrict__ g, const float* __restrict__ b,
    unsigned short* __restrict__ ob, const float* __restrict__ posf,
    unsigned short* __restrict__ qb)
{
  const long m = blockIdx.x * 4 + (threadIdx.x >> 6);
  const int lane = threadIdx.x & 63;
  const long base = m * 256 + lane * 4;
  float4 a = *(const float4*)(out + base);
  float4 d = *(const float4*)(delta + base);
  float x0 = a.x + d.x, x1 = a.y + d.y, x2 = a.z + d.z, x3 = a.w + d.w;
  float s = x0 + x1 + x2 + x3;
#pragma unroll
  for (int o = 32; o > 0; o >>= 1) s += __shfl_xor(s, o);
  float mean = s * (1.f / 256.f);
  float d0 = x0 - mean, d1 = x1 - mean, d2 = x2 - mean, d3 = x3 - mean;
  float s2 = d0 * d0 + d1 * d1 + d2 * d2 + d3 * d3;
#pragma unroll
  for (int o = 32; o > 0; o >>= 1) s2 += __shfl_xor(s2, o);
  float rs = rsqrtf(s2 * (1.f / 256.f) + 1e-5f);
  float4 gv = *(const float4*)(g + lane * 4);
  float4 bv = *(const float4*)(b + lane * 4);
  float r0 = d0 * rs * gv.x + bv.x, r1 = d1 * rs * gv.y + bv.y;
  float r2 = d2 * rs * gv.z + bv.z, r3 = d3 * rs * gv.w + bv.w;
  *(float4*)(out + base) = float4{r0, r1, r2, r3};
  ushort4 o4; o4.x = f2b(r0); o4.y = f2b(r1); o4.z = f2b(r2); o4.w = f2b(r3);
  *(ushort4*)(ob + base) = o4;
  if (QB) {
    float4 pf = *(const float4*)(posf + base);
    ushort4 q4;
    q4.x = f2b(r0 + pf.x); q4.y = f2b(r1 + pf.y);
    q4.z = f2b(r2 + pf.z); q4.w = f2b(r3 + pf.w);
    *(ushort4*)(qb + base) = q4;
  }
}

// weight transpose+convert+pad: outT[l][n][k] = n<N ? bf16(in[l][k][n]) : 0
__global__ __launch_bounds__(256) void wtrans_pad(
    const float* __restrict__ in, unsigned short* __restrict__ outT,
    int K, int N, int Npad)
{
  int idx = blockIdx.x * 256 + threadIdx.x;
  if (idx >= Npad * K) return;
  int n = idx / K, k = idx % K;
  unsigned short v = 0;
  if (n < N) v = f2b(in[(long)blockIdx.z * K * N + (long)k * N + n]);
  outT[(long)blockIdx.z * Npad * K + idx] = v;
}

__global__ __launch_bounds__(256) void wconvert(
    const float* __restrict__ in, unsigned short* __restrict__ out, int n)
{
  int idx = blockIdx.x * 256 + threadIdx.x;
  if (idx < n) out[idx] = f2b(in[idx]);
}

// outc (6,co,ci,3,3) -> (6,co,tap,ci) bf16
__global__ __launch_bounds__(256) void wpermconv(
    const float* __restrict__ in, unsigned short* __restrict__ out)
{
  int idx = blockIdx.x * 256 + threadIdx.x;
  const int ci = idx & 255;
  const int t  = (idx >> 8) % 9;
  const int co = ((idx >> 8) / 9) % 256;
  const int l  = idx / (256 * 9 * 256);
  out[idx] = f2b(in[(((long)l * 256 + co) * 256 + ci) * 9 + t]);
}

// src/pos (bt,C,HW) -> outbuf fp32, ob bf16, qb bf16, posf fp32
__global__ __launch_bounds__(256) void init_level(
    const float* __restrict__ src, const float* __restrict__ pos,
    const float* __restrict__ emb, float* __restrict__ outp,
    float* __restrict__ posf, unsigned short* __restrict__ ob,
    unsigned short* __restrict__ qb, int HW, int start)
{
  __shared__ float t1[32][33];
  __shared__ float t2[32][33];
  const int bt = blockIdx.z;
  const int p0 = blockIdx.x * 32, c0 = blockIdx.y * 32;
  const int tx = threadIdx.x, ty = threadIdx.y;
  const float* sb = src + ((long)bt * 256 + c0) * HW + p0;
  const float* pb = pos + ((long)bt * 256 + c0) * HW + p0;
#pragma unroll
  for (int j = 0; j < 4; j++) {
    int cc = ty + j * 8;
    t1[cc][tx] = sb[(long)cc * HW + tx];
    t2[cc][tx] = pb[(long)cc * HW + tx];
  }
  __syncthreads();
#pragma unroll
  for (int j = 0; j < 4; j++) {
    int pp = ty + j * 8;
    long row = (long)bt * kLQ + start + p0 + pp;
    float v = t1[tx][pp];
    float pv = t2[tx][pp] + emb[c0 + tx];
    outp[row * 256 + c0 + tx] = v;
    ob[row * 256 + c0 + tx] = f2b(v);
    qb[row * 256 + c0 + tx] = f2b(v + pv);
    posf[row * 256 + c0 + tx] = pv;
  }
}

// mask_in (b,c,t,128,128) -> mf_hwc fp32 + mc bf16
__global__ __launch_bounds__(256) void init_mask(
    const float* __restrict__ in, float* __restrict__ mf,
    unsigned short* __restrict__ mc)
{
  __shared__ float t[32][33];
  const int bt = blockIdx.z, b = bt >> 1, tt = bt & 1;
  const int p0 = blockIdx.x * 32, c0 = blockIdx.y * 32;
  const int tx = threadIdx.x, ty = threadIdx.y;
  const float* base = in + (((long)b * 256 + c0) * 2 + tt) * 16384 + p0;
#pragma unroll
  for (int j = 0; j < 4; j++) {
    int cc = ty + j * 8;
    t[cc][tx] = base[(long)cc * 32768 + tx];
  }
  __syncthreads();
#pragma unroll
  for (int j = 0; j < 4; j++) {
    int pp = ty + j * 8;
    long idx = ((long)bt * 16384 + p0 + pp) * 256 + c0 + tx;
    float v = t[tx][pp];
    mf[idx] = v;
    mc[idx] = f2b(v);
  }
}

// mf_hwc -> d_out mask region (b,c,t,128,128) fp32
__global__ __launch_bounds__(256) void hwc_to_out(
    const float* __restrict__ mf, float* __restrict__ outm)
{
  __shared__ float t[32][33];
  const int bt = blockIdx.z, b = bt >> 1, tt = bt & 1;
  const int p0 = blockIdx.x * 32, c0 = blockIdx.y * 32;
  const int tx = threadIdx.x, ty = threadIdx.y;
#pragma unroll
  for (int j = 0; j < 4; j++) {
    int pp = ty + j * 8;
    t[pp][tx] = mf[((long)bt * 16384 + p0 + pp) * 256 + c0 + tx];
  }
  __syncthreads();
#pragma unroll
  for (int j = 0; j < 4; j++) {
    int cc = ty + j * 8;
    outm[(((long)b * 256 + c0 + cc) * 2 + tt) * 16384 + p0 + tx] = t[tx][cc];
  }
}

// ---------------------------------------------------------------------------
extern "C" void kernel_launch(void* const* d_in, const int* in_sizes, int n_in,
                              void* d_out, int out_size, void* d_ws, size_t ws_size,
                              hipStream_t stream)
{
  const float* src[3] = {(const float*)d_in[0], (const float*)d_in[2], (const float*)d_in[4]};
  const float* pos[3] = {(const float*)d_in[1], (const float*)d_in[3], (const float*)d_in[5]};
  const float* mask_in = (const float*)d_in[6];
  const float* lemb    = (const float*)d_in[7];
  const float* off_w   = (const float*)d_in[8];
  const float* off_b   = (const float*)d_in[9];
  const float* aw_w    = (const float*)d_in[10];
  const float* aw_b    = (const float*)d_in[11];
  const float* val_w   = (const float*)d_in[12];
  const float* val_b   = (const float*)d_in[13];
  const float* out_w   = (const float*)d_in[14];
  const float* out_b   = (const float*)d_in[15];
  const float* ln1_g   = (const float*)d_in[16];
  const float* ln1_b   = (const float*)d_in[17];
  const float* ff1_w   = (const float*)d_in[18];
  const float* ff1_b   = (const float*)d_in[19];
  const float* ff2_w   = (const float*)d_in[20];
  const float* ff2_b   = (const float*)d_in[21];
  const float* ln2_g   = (const float*)d_in[22];
  const float* ln2_b   = (const float*)d_in[23];
  const float* lat_w   = (const float*)d_in[24];
  const float* lat_b   = (const float*)d_in[25];
  const float* outc_w  = (const float*)d_in[26];
  const float* outc_b  = (const float*)d_in[27];

  float* outbuf = (float*)d_out;                    // (4,5376,256)
  float* maskf  = (float*)d_out + 5505024;          // (2,256,2,128,128)

  char* wp = (char*)d_ws;
  auto alloc = [&](size_t bytes) {
    char* p = wp;
    wp += (bytes + 255) & ~(size_t)255;
    return p;
  };
  float*          posf  = (float*)alloc(5505024ull * 4);
  unsigned short* qb    = (unsigned short*)alloc(5505024ull * 2);
  unsigned short* ob    = (unsigned short*)alloc(5505024ull * 2);
  unsigned short* vbuf  = (unsigned short*)alloc(5505024ull * 2);
  float*          offb  = (float*)alloc(4128768ull * 4);
  float*          awb   = (float*)alloc(2064384ull * 4);
  unsigned short* attnb = (unsigned short*)alloc(5505024ull * 2);
  float*          tmp1  = (float*)alloc(5505024ull * 4);
  unsigned short* ffh   = (unsigned short*)alloc(22020096ull * 2);
  unsigned short* mc    = (unsigned short*)alloc(16777216ull * 2);
  unsigned short* xb    = (unsigned short*)alloc(16777216ull * 2);
  float*          mfh   = (float*)alloc(16777216ull * 4);
  unsigned short* valT  = (unsigned short*)alloc(6ull * 65536 * 2);
  unsigned short* offT  = (unsigned short*)alloc(6ull * 65536 * 2);
  unsigned short* awT   = (unsigned short*)alloc(6ull * 32768 * 2);
  unsigned short* outT  = (unsigned short*)alloc(6ull * 65536 * 2);
  unsigned short* ff1T  = (unsigned short*)alloc(6ull * 262144 * 2);
  unsigned short* ff2T  = (unsigned short*)alloc(6ull * 262144 * 2);
  unsigned short* latT  = (unsigned short*)alloc(6ull * 65536 * 2);
  unsigned short* outcT = (unsigned short*)alloc(6ull * 589824 * 2);

  // ---- weight prep ----
  wtrans_pad<<<dim3(256, 1, 6), 256, 0, stream>>>(val_w, valT, 256, 256, 256);
  wtrans_pad<<<dim3(256, 1, 6), 256, 0, stream>>>(off_w, offT, 256, 192, 256);
  wtrans_pad<<<dim3(128, 1, 6), 256, 0, stream>>>(aw_w,  awT,  256, 96, 128);
  wtrans_pad<<<dim3(256, 1, 6), 256, 0, stream>>>(out_w, outT, 256, 256, 256);
  wtrans_pad<<<dim3(1024, 1, 6), 256, 0, stream>>>(ff1_w, ff1T, 256, 1024, 1024);
  wtrans_pad<<<dim3(1024, 1, 6), 256, 0, stream>>>(ff2_w, ff2T, 1024, 256, 256);
  wconvert<<<dim3(1536), 256, 0, stream>>>(lat_w, latT, 6 * 65536);
  wpermconv<<<dim3(13824), 256, 0, stream>>>(outc_w, outcT);

  // ---- init ----
  const int hw[3] = {256, 1024, 4096};
  const int st[3] = {0, 256, 1280};
  for (int l = 0; l < 3; l++)
    init_level<<<dim3(hw[l] / 32, 8, 4), dim3(32, 8), 0, stream>>>(
        src[l], pos[l], lemb + l * 256, outbuf, posf, ob, qb, hw[l], st[l]);
  init_mask<<<dim3(512, 8, 4), dim3(32, 8), 0, stream>>>(mask_in, mfh, mc);

  // ---- layers ----
  for (int i = 0; i < 6; i++) {
    gemm128<1><<<dim3(168, 2), 256, 0, stream>>>(
        ob, valT + (long)i * 65536, val_b + i * 256, vbuf, 21504, 256, 256, nullptr);
    gemm128<0><<<dim3(168, 2), 256, 0, stream>>>(
        qb, offT + (long)i * 65536, off_b + i * 192, offb, 21504, 192, 256, nullptr);
    gemm128<0><<<dim3(168, 1), 256, 0, stream>>>(
        qb, awT + (long)i * 32768, aw_b + i * 96, awb, 21504, 96, 256, nullptr);
    deform_sample<<<dim3(5376), 256, 0, stream>>>(offb, awb, vbuf, attnb);
    gemm128<0><<<dim3(168, 2), 256, 0, stream>>>(
        attnb, outT + (long)i * 65536, out_b + i * 256, tmp1, 21504, 256, 256, nullptr);
    ln_row<false><<<dim3(5376), 256, 0, stream>>>(
        outbuf, tmp1, ln1_g + i * 256, ln1_b + i * 256, ob, nullptr, nullptr);
    gemm128<2><<<dim3(168, 8), 256, 0, stream>>>(
        ob, ff1T + (long)i * 262144, ff1_b + i * 1024, ffh, 21504, 1024, 256, nullptr);
    gemm128<0><<<dim3(168, 2), 256, 0, stream>>>(
        ffh, ff2T + (long)i * 262144, ff2_b + i * 256, tmp1, 21504, 256, 1024, nullptr);
    ln_row<true><<<dim3(5376), 256, 0, stream>>>(
        outbuf, tmp1, ln2_g + i * 256, ln2_b + i * 256, ob, posf, qb);
    // FPN: lat 1x1 conv + fused bilinear resize-add -> xb; 3x3 conv -> mfh/mc
    gemm128<3><<<dim3(512, 2), 256, 0, stream>>>(
        mc, latT + (long)i * 65536, lat_b + i * 256, xb, 65536, 256, 256, outbuf);
    conv3x3<<<dim3(128, 2, 4), 256, 0, stream>>>(
        xb, outcT + (long)i * 589824, outc_b + i * 256, mfh, mc);
  }
  hwc_to_out<<<dim3(512, 8, 4), dim3(32, 8), 0, stream>>>(mfh, maskf);
}

// Round 5
// 2828.322 us; speedup vs baseline: 1.3624x; 1.0851x over previous
//
#include <hip/hip_runtime.h>

#define DEV __device__ __forceinline__

using f32x4  = __attribute__((ext_vector_type(4))) float;
using bf16x8 = __attribute__((ext_vector_type(8))) short;

static constexpr int kLQ = 5376;

DEV unsigned short f2b(float f) {
  unsigned u = __builtin_bit_cast(unsigned, f);
  u = u + 0x7fffu + ((u >> 16) & 1u);
  return (unsigned short)(u >> 16);
}
DEV float b2f(unsigned short s) {
  unsigned u = ((unsigned)s) << 16;
  return __builtin_bit_cast(float, u);
}

DEV void glds16(const void* g, void* l) {
  __builtin_amdgcn_global_load_lds(
      (const __attribute__((address_space(1))) void*)g,
      (__attribute__((address_space(3))) void*)l, 16, 0, 0);
}

// ---------------------------------------------------------------------------
// gemm128: C[M][N] = A[M][K](bf16) * Bt[Npad][K](bf16, zero-padded) + bias
// 128x128 tile, BK=32, 4 waves (2x2), wave 64x64 = 4x4 16x16x32 MFMA frags.
// A,B via global_load_lds 16B, XOR-swizzled per-lane source (rule #21).
// EPI: 0 fp32, 1 bf16, 2 relu->bf16, 3 bf16 + fused bilinear-resize add.
// ---------------------------------------------------------------------------
template<int EPI>
__global__ __launch_bounds__(256) void gemm128(
    const unsigned short* __restrict__ A, const unsigned short* __restrict__ Bt,
    const float* __restrict__ bias, void* __restrict__ Cp,
    int M, int N, int K, const float* __restrict__ rsrc)
{
  __shared__ unsigned short As[128 * 32];
  __shared__ unsigned short Bs[128 * 32];
  const int tid = threadIdx.x, lane = tid & 63, wid = tid >> 6;
  const int m0 = blockIdx.x * 128, n0 = blockIdx.y * 128;
  const int wr = wid >> 1, wc = wid & 1;
  const int l15 = lane & 15, lg = lane >> 4;

  const int s0 = wid * 64 + lane, s1 = 256 + s0;
  const int r0 = s0 >> 2, cs0 = (s0 & 3) ^ ((r0 >> 1) & 3);
  const int r1 = s1 >> 2, cs1 = (s1 & 3) ^ ((r1 >> 1) & 3);
  const unsigned short* Ag0 = A + (long)(m0 + r0) * K + cs0 * 8;
  const unsigned short* Ag1 = A + (long)(m0 + r1) * K + cs1 * 8;
  const unsigned short* Bg0 = Bt + (long)(n0 + r0) * K + cs0 * 8;
  const unsigned short* Bg1 = Bt + (long)(n0 + r1) * K + cs1 * 8;
  unsigned short* Al0 = As + (wid * 64) * 8;
  unsigned short* Al1 = As + (256 + wid * 64) * 8;
  unsigned short* Bl0 = Bs + (wid * 64) * 8;
  unsigned short* Bl1 = Bs + (256 + wid * 64) * 8;

  f32x4 acc[4][4];
#pragma unroll
  for (int i = 0; i < 4; i++)
#pragma unroll
    for (int j = 0; j < 4; j++) acc[i][j] = f32x4{0.f, 0.f, 0.f, 0.f};

  for (int k0 = 0; k0 < K; k0 += 32) {
    glds16(Ag0 + k0, Al0);
    glds16(Ag1 + k0, Al1);
    glds16(Bg0 + k0, Bl0);
    glds16(Bg1 + k0, Bl1);
    __syncthreads();
    bf16x8 a[4], b[4];
#pragma unroll
    for (int i = 0; i < 4; i++) {
      int ra = wr * 64 + i * 16 + l15;
      a[i] = *(const bf16x8*)(As + ra * 32 + (lg ^ ((ra >> 1) & 3)) * 8);
      int rb = wc * 64 + i * 16 + l15;
      b[i] = *(const bf16x8*)(Bs + rb * 32 + (lg ^ ((rb >> 1) & 3)) * 8);
    }
#pragma unroll
    for (int mi = 0; mi < 4; mi++)
#pragma unroll
      for (int nj = 0; nj < 4; nj++)
        acc[mi][nj] = __builtin_amdgcn_mfma_f32_16x16x32_bf16(
            a[mi], b[nj], acc[mi][nj], 0, 0, 0);
    __syncthreads();
  }

  // EPI==3: block covers one image row (bt, y) of the 128x128 output.
  int ry0 = 0, ry1 = 0;
  float rfy = 0.f;
  const float* rb0 = nullptr;
  if (EPI == 3) {
    const int bt = m0 >> 14, y = (m0 & 16383) >> 7;
    float sy = y * 0.5f - 0.25f;
    float y0f = floorf(sy);
    rfy = sy - y0f;
    ry0 = min(63, max(0, (int)y0f));
    ry1 = min(63, max(0, (int)y0f + 1));
    rb0 = rsrc + ((long)bt * kLQ + 1280) * 256;
  }

#pragma unroll
  for (int mi = 0; mi < 4; mi++)
#pragma unroll
    for (int nj = 0; nj < 4; nj++) {
      int col = n0 + wc * 64 + nj * 16 + l15;
      if (col >= N) continue;
      float bb = bias[col];
#pragma unroll
      for (int rr = 0; rr < 4; rr++) {
        long row = m0 + wr * 64 + mi * 16 + lg * 4 + rr;
        float v = acc[mi][nj][rr] + bb;
        if (EPI == 2) v = fmaxf(v, 0.f);
        if (EPI == 3) {
          int x = wr * 64 + mi * 16 + lg * 4 + rr;
          float sx = x * 0.5f - 0.25f;
          float x0f = floorf(sx);
          float fx = sx - x0f;
          int x0 = min(63, max(0, (int)x0f)), x1 = min(63, max(0, (int)x0f + 1));
          float v00 = rb0[(long)(ry0 * 64 + x0) * 256 + col];
          float v01 = rb0[(long)(ry0 * 64 + x1) * 256 + col];
          float v10 = rb0[(long)(ry1 * 64 + x0) * 256 + col];
          float v11 = rb0[(long)(ry1 * 64 + x1) * 256 + col];
          v += (1.f - rfy) * ((1.f - fx) * v00 + fx * v01)
             + rfy * ((1.f - fx) * v10 + fx * v11);
        }
        if (EPI == 0) ((float*)Cp)[row * N + col] = v;
        else ((unsigned short*)Cp)[row * N + col] = f2b(v);
      }
    }
}

// ---------------------------------------------------------------------------
// 3x3 conv implicit GEMM, tile = 128 px (one image row) x 128 co.
// Per ci-chunk (8 of 32): stage 3-row halo [3][128px][32ci] in LDS once,
// then 9 taps x 16 MFMA with x-shift applied at ds_read time (edge lanes
// zero-selected). B-fragments read directly from global (L2-resident),
// layout [tap][chunk][co][32ci]. One barrier pair per chunk (8 vs 72).
// Epilogue: mf += relu(conv+bias) (fp32 NHWC) and mc = bf16(mf).
// ---------------------------------------------------------------------------
__global__ __launch_bounds__(256) void conv3x3(
    const unsigned short* __restrict__ xb, const unsigned short* __restrict__ wT,
    const float* __restrict__ bias, float* __restrict__ mf,
    unsigned short* __restrict__ mc)
{
  __shared__ unsigned short As[3 * 128 * 32];   // 24 KB
  const int tid = threadIdx.x, lane = tid & 63, wid = tid >> 6;
  const int y = blockIdx.x, c0 = blockIdx.y * 128, bt = blockIdx.z;
  const int wr = wid >> 1, wc = wid & 1;
  const int l15 = lane & 15, lg = lane >> 4;
  const unsigned short* xbb = xb + (long)bt * (16384 * 256);
  const bool zr0 = (y == 0), zr2 = (y == 127);

  f32x4 acc[4][4];
#pragma unroll
  for (int i = 0; i < 4; i++)
#pragma unroll
    for (int j = 0; j < 4; j++) acc[i][j] = f32x4{0.f, 0.f, 0.f, 0.f};

  for (int s = 0; s < 8; s++) {
    const int ci0 = s * 32;
    // ---- stage 3-row halo, this ci chunk: 1536 16B slots, 6 per thread ----
#pragma unroll
    for (int k = 0; k < 6; k++) {
      const int S = k * 256 + tid;            // wave-contiguous slots
      const int r = S >> 9;                   // wave-uniform
      const int p = (S >> 2) & 127;
      const int cs = (S & 3) ^ ((p >> 1) & 3);
      if ((r == 0 && zr0) || (r == 2 && zr2)) {
        *(uint4*)(As + S * 8) = uint4{0u, 0u, 0u, 0u};
      } else {
        glds16(xbb + ((long)((y + r - 1) * 128 + p) * 256 + ci0 + cs * 8),
               As + (k * 256 + wid * 64) * 8);
      }
    }
    __syncthreads();
    // ---- 9 taps x 16 MFMA ----
#pragma unroll
    for (int r = 0; r < 3; r++) {
#pragma unroll
      for (int dxi = 0; dxi < 3; dxi++) {
        const int t = r * 3 + dxi, dx = dxi - 1;
        const unsigned short* wb = wT + (((long)t * 8 + s) * 256) * 32;
        bf16x8 a[4], b[4];
#pragma unroll
        for (int i = 0; i < 4; i++) {
          const int co_r = c0 + wc * 64 + i * 16 + l15;
          b[i] = *(const bf16x8*)(wb + co_r * 32 + lg * 8);
          const int px = wr * 64 + i * 16 + l15 + dx;
          const int pxc = min(127, max(0, px));
          bf16x8 v = *(const bf16x8*)(
              As + ((r * 128 + pxc) * 4 + (lg ^ ((pxc >> 1) & 3))) * 8);
          if ((unsigned)px >= 128u) v = bf16x8{0, 0, 0, 0, 0, 0, 0, 0};
          a[i] = v;
        }
#pragma unroll
        for (int mi = 0; mi < 4; mi++)
#pragma unroll
          for (int nj = 0; nj < 4; nj++)
            acc[mi][nj] = __builtin_amdgcn_mfma_f32_16x16x32_bf16(
                a[mi], b[nj], acc[mi][nj], 0, 0, 0);
      }
    }
    __syncthreads();
  }

#pragma unroll
  for (int mi = 0; mi < 4; mi++)
#pragma unroll
    for (int nj = 0; nj < 4; nj++) {
      int co = c0 + wc * 64 + nj * 16 + l15;
      float bb = bias[co];
#pragma unroll
      for (int rr = 0; rr < 4; rr++) {
        int x = wr * 64 + mi * 16 + lg * 4 + rr;
        long idx = ((long)bt * 16384 + y * 128 + x) * 256 + co;
        float v = mf[idx] + fmaxf(acc[mi][nj][rr] + bb, 0.f);
        mf[idx] = v;
        mc[idx] = f2b(v);
      }
    }
}

// ---------------------------------------------------------------------------
// Deformable-attention sampling + fused softmax.
// 64 threads per query: h = t>>3 (8 heads), d4 = t&7 (4 channels each).
// ---------------------------------------------------------------------------
__global__ __launch_bounds__(256) void deform_sample(
    const float* __restrict__ offp, const float* __restrict__ awlog,
    const unsigned short* __restrict__ vp, unsigned short* __restrict__ attn)
{
  const int m = blockIdx.x * 4 + (threadIdx.x >> 6);
  const int t = threadIdx.x & 63;
  const int h = t >> 3, d4 = t & 7;
  const int bt = m / kLQ, q = m % kLQ;
  int pq, Wq;
  if (q < 256)       { pq = q;        Wq = 16; }
  else if (q < 1280) { pq = q - 256;  Wq = 32; }
  else               { pq = q - 1280; Wq = 64; }
  const float refx = ((pq % Wq) + 0.5f) / Wq;
  const float refy = ((pq / Wq) + 0.5f) / Wq;
  const int starts[3] = {0, 256, 1280};
  const int dims[3]   = {16, 32, 64};

  const float4* offr = (const float4*)(offp + (long)m * 192 + h * 24);
  const float4* awr  = (const float4*)(awlog + (long)m * 96 + h * 12);
  float off[24], aw[12];
#pragma unroll
  for (int j = 0; j < 6; j++) {
    float4 v = offr[j];
    off[j * 4] = v.x; off[j * 4 + 1] = v.y; off[j * 4 + 2] = v.z; off[j * 4 + 3] = v.w;
  }
#pragma unroll
  for (int j = 0; j < 3; j++) {
    float4 v = awr[j];
    aw[j * 4] = v.x; aw[j * 4 + 1] = v.y; aw[j * 4 + 2] = v.z; aw[j * 4 + 3] = v.w;
  }
  float mx = aw[0];
#pragma unroll
  for (int j = 1; j < 12; j++) mx = fmaxf(mx, aw[j]);
  float ssum = 0.f;
#pragma unroll
  for (int j = 0; j < 12; j++) { float e = __expf(aw[j] - mx); aw[j] = e; ssum += e; }
  float inv = 1.f / ssum;

  const unsigned short* vb = vp + ((long)bt * kLQ) * 256 + h * 32 + d4 * 4;
  float ax = 0.f, ay = 0.f, az = 0.f, aww = 0.f;
#pragma unroll
  for (int l = 0; l < 3; l++) {
    const int Wl = dims[l];
    const float winv = 1.f / (float)Wl;
    const int st = starts[l];
#pragma unroll
    for (int p = 0; p < 4; p++) {
      float ox = off[l * 8 + p * 2], oy = off[l * 8 + p * 2 + 1];
      float a  = aw[l * 4 + p] * inv;
      float fxp = (refx + ox * winv) * Wl - 0.5f;
      float fyp = (refy + oy * winv) * Wl - 0.5f;
      float x0f = floorf(fxp), y0f = floorf(fyp);
      int x0 = (int)x0f, y0 = (int)y0f;
      float fx = fxp - x0f, fy = fyp - y0f;
      float sx = 0.f, sy = 0.f, sz = 0.f, sw = 0.f;
#pragma unroll
      for (int cy = 0; cy < 2; cy++)
#pragma unroll
        for (int cx = 0; cx < 2; cx++) {
          int ix = x0 + cx, iy = y0 + cy;
          if ((unsigned)ix < (unsigned)Wl && (unsigned)iy < (unsigned)Wl) {
            float w = (cx ? fx : 1.f - fx) * (cy ? fy : 1.f - fy);
            ushort4 u = *(const ushort4*)(vb + (long)(st + iy * Wl + ix) * 256);
            sx += w * b2f(u.x); sy += w * b2f(u.y);
            sz += w * b2f(u.z); sw += w * b2f(u.w);
          }
        }
      ax += a * sx; ay += a * sy; az += a * sz; aww += a * sw;
    }
  }
  ushort4 r;
  r.x = f2b(ax); r.y = f2b(ay); r.z = f2b(az); r.w = f2b(aww);
  *(ushort4*)(attn + (long)m * 256 + h * 32 + d4 * 4) = r;
}

// ---------------------------------------------------------------------------
// LN: one wave per row, float4 per lane, shfl_xor butterfly (no LDS).
// ---------------------------------------------------------------------------
template<bool QB>
__global__ __launch_bounds__(256) void ln_row(
    float* __restrict__ out, const float* __restrict__ delta,
    const float* __restrict__ g, const float* __restrict__ b,
    unsigned short* __restrict__ ob, const float* __restrict__ posf,
    unsigned short* __restrict__ qb)
{
  const long m = blockIdx.x * 4 + (threadIdx.x >> 6);
  const int lane = threadIdx.x & 63;
  const long base = m * 256 + lane * 4;
  float4 a = *(const float4*)(out + base);
  float4 d = *(const float4*)(delta + base);
  float x0 = a.x + d.x, x1 = a.y + d.y, x2 = a.z + d.z, x3 = a.w + d.w;
  float s = x0 + x1 + x2 + x3;
#pragma unroll
  for (int o = 32; o > 0; o >>= 1) s += __shfl_xor(s, o);
  float mean = s * (1.f / 256.f);
  float d0 = x0 - mean, d1 = x1 - mean, d2 = x2 - mean, d3 = x3 - mean;
  float s2 = d0 * d0 + d1 * d1 + d2 * d2 + d3 * d3;
#pragma unroll
  for (int o = 32; o > 0; o >>= 1) s2 += __shfl_xor(s2, o);
  float rs = rsqrtf(s2 * (1.f / 256.f) + 1e-5f);
  float4 gv = *(const float4*)(g + lane * 4);
  float4 bv = *(const float4*)(b + lane * 4);
  float r0 = d0 * rs * gv.x + bv.x, r1 = d1 * rs * gv.y + bv.y;
  float r2 = d2 * rs * gv.z + bv.z, r3 = d3 * rs * gv.w + bv.w;
  *(float4*)(out + base) = float4{r0, r1, r2, r3};
  ushort4 o4; o4.x = f2b(r0); o4.y = f2b(r1); o4.z = f2b(r2); o4.w = f2b(r3);
  *(ushort4*)(ob + base) = o4;
  if (QB) {
    float4 pf = *(const float4*)(posf + base);
    ushort4 q4;
    q4.x = f2b(r0 + pf.x); q4.y = f2b(r1 + pf.y);
    q4.z = f2b(r2 + pf.z); q4.w = f2b(r3 + pf.w);
    *(ushort4*)(qb + base) = q4;
  }
}

// weight transpose+convert+pad: outT[l][n][k] = n<N ? bf16(in[l][k][n]) : 0
__global__ __launch_bounds__(256) void wtrans_pad(
    const float* __restrict__ in, unsigned short* __restrict__ outT,
    int K, int N, int Npad)
{
  int idx = blockIdx.x * 256 + threadIdx.x;
  if (idx >= Npad * K) return;
  int n = idx / K, k = idx % K;
  unsigned short v = 0;
  if (n < N) v = f2b(in[(long)blockIdx.z * K * N + (long)k * N + n]);
  outT[(long)blockIdx.z * Npad * K + idx] = v;
}

__global__ __launch_bounds__(256) void wconvert(
    const float* __restrict__ in, unsigned short* __restrict__ out, int n)
{
  int idx = blockIdx.x * 256 + threadIdx.x;
  if (idx < n) out[idx] = f2b(in[idx]);
}

// outc (6,co,ci,3,3) -> [l][tap][ci-chunk][co][32ci] bf16
__global__ __launch_bounds__(256) void wpermconv(
    const float* __restrict__ in, unsigned short* __restrict__ out)
{
  int idx = blockIdx.x * 256 + threadIdx.x;   // 6*9*256*256 exact
  const int ci = idx & 255;
  const int co = (idx >> 8) & 255;
  const int t  = (idx >> 16) % 9;
  const int l  = idx / (9 << 16);
  const int s = ci >> 5, cin = ci & 31;
  out[((((long)l * 9 + t) * 8 + s) * 256 + co) * 32 + cin] =
      f2b(in[(((long)l * 256 + co) * 256 + ci) * 9 + t]);
}

// src/pos (bt,C,HW) -> outbuf fp32, ob bf16, qb bf16, posf fp32
__global__ __launch_bounds__(256) void init_level(
    const float* __restrict__ src, const float* __restrict__ pos,
    const float* __restrict__ emb, float* __restrict__ outp,
    float* __restrict__ posf, unsigned short* __restrict__ ob,
    unsigned short* __restrict__ qb, int HW, int start)
{
  __shared__ float t1[32][33];
  __shared__ float t2[32][33];
  const int bt = blockIdx.z;
  const int p0 = blockIdx.x * 32, c0 = blockIdx.y * 32;
  const int tx = threadIdx.x, ty = threadIdx.y;
  const float* sb = src + ((long)bt * 256 + c0) * HW + p0;
  const float* pb = pos + ((long)bt * 256 + c0) * HW + p0;
#pragma unroll
  for (int j = 0; j < 4; j++) {
    int cc = ty + j * 8;
    t1[cc][tx] = sb[(long)cc * HW + tx];
    t2[cc][tx] = pb[(long)cc * HW + tx];
  }
  __syncthreads();
#pragma unroll
  for (int j = 0; j < 4; j++) {
    int pp = ty + j * 8;
    long row = (long)bt * kLQ + start + p0 + pp;
    float v = t1[tx][pp];
    float pv = t2[tx][pp] + emb[c0 + tx];
    outp[row * 256 + c0 + tx] = v;
    ob[row * 256 + c0 + tx] = f2b(v);
    qb[row * 256 + c0 + tx] = f2b(v + pv);
    posf[row * 256 + c0 + tx] = pv;
  }
}

// mask_in (b,c,t,128,128) -> mf_hwc fp32 + mc bf16
__global__ __launch_bounds__(256) void init_mask(
    const float* __restrict__ in, float* __restrict__ mf,
    unsigned short* __restrict__ mc)
{
  __shared__ float t[32][33];
  const int bt = blockIdx.z, b = bt >> 1, tt = bt & 1;
  const int p0 = blockIdx.x * 32, c0 = blockIdx.y * 32;
  const int tx = threadIdx.x, ty = threadIdx.y;
  const float* base = in + (((long)b * 256 + c0) * 2 + tt) * 16384 + p0;
#pragma unroll
  for (int j = 0; j < 4; j++) {
    int cc = ty + j * 8;
    t[cc][tx] = base[(long)cc * 32768 + tx];
  }
  __syncthreads();
#pragma unroll
  for (int j = 0; j < 4; j++) {
    int pp = ty + j * 8;
    long idx = ((long)bt * 16384 + p0 + pp) * 256 + c0 + tx;
    float v = t[tx][pp];
    mf[idx] = v;
    mc[idx] = f2b(v);
  }
}

// mf_hwc -> d_out mask region (b,c,t,128,128) fp32
__global__ __launch_bounds__(256) void hwc_to_out(
    const float* __restrict__ mf, float* __restrict__ outm)
{
  __shared__ float t[32][33];
  const int bt = blockIdx.z, b = bt >> 1, tt = bt & 1;
  const int p0 = blockIdx.x * 32, c0 = blockIdx.y * 32;
  const int tx = threadIdx.x, ty = threadIdx.y;
#pragma unroll
  for (int j = 0; j < 4; j++) {
    int pp = ty + j * 8;
    t[pp][tx] = mf[((long)bt * 16384 + p0 + pp) * 256 + c0 + tx];
  }
  __syncthreads();
#pragma unroll
  for (int j = 0; j < 4; j++) {
    int cc = ty + j * 8;
    outm[(((long)b * 256 + c0 + cc) * 2 + tt) * 16384 + p0 + tx] = t[tx][cc];
  }
}

// ---------------------------------------------------------------------------
extern "C" void kernel_launch(void* const* d_in, const int* in_sizes, int n_in,
                              void* d_out, int out_size, void* d_ws, size_t ws_size,
                              hipStream_t stream)
{
  const float* src[3] = {(const float*)d_in[0], (const float*)d_in[2], (const float*)d_in[4]};
  const float* pos[3] = {(const float*)d_in[1], (const float*)d_in[3], (const float*)d_in[5]};
  const float* mask_in = (const float*)d_in[6];
  const float* lemb    = (const float*)d_in[7];
  const float* off_w   = (const float*)d_in[8];
  const float* off_b   = (const float*)d_in[9];
  const float* aw_w    = (const float*)d_in[10];
  const float* aw_b    = (const float*)d_in[11];
  const float* val_w   = (const float*)d_in[12];
  const float* val_b   = (const float*)d_in[13];
  const float* out_w   = (const float*)d_in[14];
  const float* out_b   = (const float*)d_in[15];
  const float* ln1_g   = (const float*)d_in[16];
  const float* ln1_b   = (const float*)d_in[17];
  const float* ff1_w   = (const float*)d_in[18];
  const float* ff1_b   = (const float*)d_in[19];
  const float* ff2_w   = (const float*)d_in[20];
  const float* ff2_b   = (const float*)d_in[21];
  const float* ln2_g   = (const float*)d_in[22];
  const float* ln2_b   = (const float*)d_in[23];
  const float* lat_w   = (const float*)d_in[24];
  const float* lat_b   = (const float*)d_in[25];
  const float* outc_w  = (const float*)d_in[26];
  const float* outc_b  = (const float*)d_in[27];

  float* outbuf = (float*)d_out;                    // (4,5376,256)
  float* maskf  = (float*)d_out + 5505024;          // (2,256,2,128,128)

  char* wp = (char*)d_ws;
  auto alloc = [&](size_t bytes) {
    char* p = wp;
    wp += (bytes + 255) & ~(size_t)255;
    return p;
  };
  float*          posf  = (float*)alloc(5505024ull * 4);
  unsigned short* qb    = (unsigned short*)alloc(5505024ull * 2);
  unsigned short* ob    = (unsigned short*)alloc(5505024ull * 2);
  unsigned short* vbuf  = (unsigned short*)alloc(5505024ull * 2);
  float*          offb  = (float*)alloc(4128768ull * 4);
  float*          awb   = (float*)alloc(2064384ull * 4);
  unsigned short* attnb = (unsigned short*)alloc(5505024ull * 2);
  float*          tmp1  = (float*)alloc(5505024ull * 4);
  unsigned short* ffh   = (unsigned short*)alloc(22020096ull * 2);
  unsigned short* mc    = (unsigned short*)alloc(16777216ull * 2);
  unsigned short* xb    = (unsigned short*)alloc(16777216ull * 2);
  float*          mfh   = (float*)alloc(16777216ull * 4);
  unsigned short* valT  = (unsigned short*)alloc(6ull * 65536 * 2);
  unsigned short* offT  = (unsigned short*)alloc(6ull * 65536 * 2);
  unsigned short* awT   = (unsigned short*)alloc(6ull * 32768 * 2);
  unsigned short* outT  = (unsigned short*)alloc(6ull * 65536 * 2);
  unsigned short* ff1T  = (unsigned short*)alloc(6ull * 262144 * 2);
  unsigned short* ff2T  = (unsigned short*)alloc(6ull * 262144 * 2);
  unsigned short* latT  = (unsigned short*)alloc(6ull * 65536 * 2);
  unsigned short* outcT = (unsigned short*)alloc(6ull * 589824 * 2);

  // ---- weight prep ----
  wtrans_pad<<<dim3(256, 1, 6), 256, 0, stream>>>(val_w, valT, 256, 256, 256);
  wtrans_pad<<<dim3(256, 1, 6), 256, 0, stream>>>(off_w, offT, 256, 192, 256);
  wtrans_pad<<<dim3(128, 1, 6), 256, 0, stream>>>(aw_w,  awT,  256, 96, 128);
  wtrans_pad<<<dim3(256, 1, 6), 256, 0, stream>>>(out_w, outT, 256, 256, 256);
  wtrans_pad<<<dim3(1024, 1, 6), 256, 0, stream>>>(ff1_w, ff1T, 256, 1024, 1024);
  wtrans_pad<<<dim3(1024, 1, 6), 256, 0, stream>>>(ff2_w, ff2T, 1024, 256, 256);
  wconvert<<<dim3(1536), 256, 0, stream>>>(lat_w, latT, 6 * 65536);
  wpermconv<<<dim3(13824), 256, 0, stream>>>(outc_w, outcT);

  // ---- init ----
  const int hw[3] = {256, 1024, 4096};
  const int st[3] = {0, 256, 1280};
  for (int l = 0; l < 3; l++)
    init_level<<<dim3(hw[l] / 32, 8, 4), dim3(32, 8), 0, stream>>>(
        src[l], pos[l], lemb + l * 256, outbuf, posf, ob, qb, hw[l], st[l]);
  init_mask<<<dim3(512, 8, 4), dim3(32, 8), 0, stream>>>(mask_in, mfh, mc);

  // ---- layers ----
  for (int i = 0; i < 6; i++) {
    gemm128<1><<<dim3(168, 2), 256, 0, stream>>>(
        ob, valT + (long)i * 65536, val_b + i * 256, vbuf, 21504, 256, 256, nullptr);
    gemm128<0><<<dim3(168, 2), 256, 0, stream>>>(
        qb, offT + (long)i * 65536, off_b + i * 192, offb, 21504, 192, 256, nullptr);
    gemm128<0><<<dim3(168, 1), 256, 0, stream>>>(
        qb, awT + (long)i * 32768, aw_b + i * 96, awb, 21504, 96, 256, nullptr);
    deform_sample<<<dim3(5376), 256, 0, stream>>>(offb, awb, vbuf, attnb);
    gemm128<0><<<dim3(168, 2), 256, 0, stream>>>(
        attnb, outT + (long)i * 65536, out_b + i * 256, tmp1, 21504, 256, 256, nullptr);
    ln_row<false><<<dim3(5376), 256, 0, stream>>>(
        outbuf, tmp1, ln1_g + i * 256, ln1_b + i * 256, ob, nullptr, nullptr);
    gemm128<2><<<dim3(168, 8), 256, 0, stream>>>(
        ob, ff1T + (long)i * 262144, ff1_b + i * 1024, ffh, 21504, 1024, 256, nullptr);
    gemm128<0><<<dim3(168, 2), 256, 0, stream>>>(
        ffh, ff2T + (long)i * 262144, ff2_b + i * 256, tmp1, 21504, 256, 1024, nullptr);
    ln_row<true><<<dim3(5376), 256, 0, stream>>>(
        outbuf, tmp1, ln2_g + i * 256, ln2_b + i * 256, ob, posf, qb);
    // FPN: lat 1x1 conv + fused bilinear resize-add -> xb; 3x3 conv -> mfh/mc
    gemm128<3><<<dim3(512, 2), 256, 0, stream>>>(
        mc, latT + (long)i * 65536, lat_b + i * 256, xb, 65536, 256, 256, outbuf);
    conv3x3<<<dim3(128, 2, 4), 256, 0, stream>>>(
        xb, outcT + (long)i * 589824, outc_b + i * 256, mfh, mc);
  }
  hwc_to_out<<<dim3(512, 8, 4), dim3(32, 8), 0, stream>>>(mfh, maskf);
}

// Round 6
// 2614.329 us; speedup vs baseline: 1.4739x; 1.0819x over previous
//
#include <hip/hip_runtime.h>

#define DEV __device__ __forceinline__

using f32x4  = __attribute__((ext_vector_type(4))) float;
using bf16x8 = __attribute__((ext_vector_type(8))) short;

static constexpr int kLQ = 5376;

DEV unsigned short f2b(float f) {
  unsigned u = __builtin_bit_cast(unsigned, f);
  u = u + 0x7fffu + ((u >> 16) & 1u);
  return (unsigned short)(u >> 16);
}
DEV float b2f(unsigned short s) {
  unsigned u = ((unsigned)s) << 16;
  return __builtin_bit_cast(float, u);
}

DEV void glds16(const void* g, void* l) {
  __builtin_amdgcn_global_load_lds(
      (const __attribute__((address_space(1))) void*)g,
      (__attribute__((address_space(3))) void*)l, 16, 0, 0);
}

// ---------------------------------------------------------------------------
// gemm128: C[M][N] = A[M][K](bf16) * Bt[Npad][K](bf16, zero-padded) + bias
// 128x128 tile, BK=32, 4 waves (2x2), wave 64x64 = 4x4 16x16x32 MFMA frags.
// A,B via global_load_lds 16B, XOR-swizzled per-lane source (rule #21).
// EPI: 0 fp32, 1 bf16, 2 relu->bf16, 3 bf16 + fused bilinear-resize add.
// ---------------------------------------------------------------------------
template<int EPI>
__global__ __launch_bounds__(256) void gemm128(
    const unsigned short* __restrict__ A, const unsigned short* __restrict__ Bt,
    const float* __restrict__ bias, void* __restrict__ Cp,
    int M, int N, int K, const float* __restrict__ rsrc)
{
  __shared__ unsigned short As[128 * 32];
  __shared__ unsigned short Bs[128 * 32];
  const int tid = threadIdx.x, lane = tid & 63, wid = tid >> 6;
  const int m0 = blockIdx.x * 128, n0 = blockIdx.y * 128;
  const int wr = wid >> 1, wc = wid & 1;
  const int l15 = lane & 15, lg = lane >> 4;

  const int s0 = wid * 64 + lane, s1 = 256 + s0;
  const int r0 = s0 >> 2, cs0 = (s0 & 3) ^ ((r0 >> 1) & 3);
  const int r1 = s1 >> 2, cs1 = (s1 & 3) ^ ((r1 >> 1) & 3);
  const unsigned short* Ag0 = A + (long)(m0 + r0) * K + cs0 * 8;
  const unsigned short* Ag1 = A + (long)(m0 + r1) * K + cs1 * 8;
  const unsigned short* Bg0 = Bt + (long)(n0 + r0) * K + cs0 * 8;
  const unsigned short* Bg1 = Bt + (long)(n0 + r1) * K + cs1 * 8;
  unsigned short* Al0 = As + (wid * 64) * 8;
  unsigned short* Al1 = As + (256 + wid * 64) * 8;
  unsigned short* Bl0 = Bs + (wid * 64) * 8;
  unsigned short* Bl1 = Bs + (256 + wid * 64) * 8;

  f32x4 acc[4][4];
#pragma unroll
  for (int i = 0; i < 4; i++)
#pragma unroll
    for (int j = 0; j < 4; j++) acc[i][j] = f32x4{0.f, 0.f, 0.f, 0.f};

  for (int k0 = 0; k0 < K; k0 += 32) {
    glds16(Ag0 + k0, Al0);
    glds16(Ag1 + k0, Al1);
    glds16(Bg0 + k0, Bl0);
    glds16(Bg1 + k0, Bl1);
    __syncthreads();
    bf16x8 a[4], b[4];
#pragma unroll
    for (int i = 0; i < 4; i++) {
      int ra = wr * 64 + i * 16 + l15;
      a[i] = *(const bf16x8*)(As + ra * 32 + (lg ^ ((ra >> 1) & 3)) * 8);
      int rb = wc * 64 + i * 16 + l15;
      b[i] = *(const bf16x8*)(Bs + rb * 32 + (lg ^ ((rb >> 1) & 3)) * 8);
    }
#pragma unroll
    for (int mi = 0; mi < 4; mi++)
#pragma unroll
      for (int nj = 0; nj < 4; nj++)
        acc[mi][nj] = __builtin_amdgcn_mfma_f32_16x16x32_bf16(
            a[mi], b[nj], acc[mi][nj], 0, 0, 0);
    __syncthreads();
  }

  // EPI==3: block covers one image row (bt, y) of the 128x128 output.
  int ry0 = 0, ry1 = 0;
  float rfy = 0.f;
  const float* rb0 = nullptr;
  if (EPI == 3) {
    const int bt = m0 >> 14, y = (m0 & 16383) >> 7;
    float sy = y * 0.5f - 0.25f;
    float y0f = floorf(sy);
    rfy = sy - y0f;
    ry0 = min(63, max(0, (int)y0f));
    ry1 = min(63, max(0, (int)y0f + 1));
    rb0 = rsrc + ((long)bt * kLQ + 1280) * 256;
  }

#pragma unroll
  for (int mi = 0; mi < 4; mi++)
#pragma unroll
    for (int nj = 0; nj < 4; nj++) {
      int col = n0 + wc * 64 + nj * 16 + l15;
      if (col >= N) continue;
      float bb = bias[col];
#pragma unroll
      for (int rr = 0; rr < 4; rr++) {
        long row = m0 + wr * 64 + mi * 16 + lg * 4 + rr;
        float v = acc[mi][nj][rr] + bb;
        if (EPI == 2) v = fmaxf(v, 0.f);
        if (EPI == 3) {
          int x = wr * 64 + mi * 16 + lg * 4 + rr;
          float sx = x * 0.5f - 0.25f;
          float x0f = floorf(sx);
          float fx = sx - x0f;
          int x0 = min(63, max(0, (int)x0f)), x1 = min(63, max(0, (int)x0f + 1));
          float v00 = rb0[(long)(ry0 * 64 + x0) * 256 + col];
          float v01 = rb0[(long)(ry0 * 64 + x1) * 256 + col];
          float v10 = rb0[(long)(ry1 * 64 + x0) * 256 + col];
          float v11 = rb0[(long)(ry1 * 64 + x1) * 256 + col];
          v += (1.f - rfy) * ((1.f - fx) * v00 + fx * v01)
             + rfy * ((1.f - fx) * v10 + fx * v11);
        }
        if (EPI == 0) ((float*)Cp)[row * N + col] = v;
        else ((unsigned short*)Cp)[row * N + col] = f2b(v);
      }
    }
}

// ---------------------------------------------------------------------------
// 3x3 conv implicit GEMM, tile = 128 px (one image row) x 128 co.
// Double-buffered ci-chunk staging (2-phase): issue next-chunk glds BEFORE
// the 144 MFMAs of the current chunk; one barrier per chunk. LDS 2x24KB.
// mask_features accumulate entirely in bf16 mc: mc += relu(conv+bias).
// B-fragments straight from global (L2-resident), layout [tap][chunk][co][32ci].
// ---------------------------------------------------------------------------
__global__ __launch_bounds__(256) void conv3x3(
    const unsigned short* __restrict__ xb, const unsigned short* __restrict__ wT,
    const float* __restrict__ bias, unsigned short* __restrict__ mc)
{
  __shared__ unsigned short As[2 * 3 * 128 * 32];   // 2 x 24 KB
  const int tid = threadIdx.x, lane = tid & 63, wid = tid >> 6;
  const int y = blockIdx.x, c0 = blockIdx.y * 128, bt = blockIdx.z;
  const int wr = wid >> 1, wc = wid & 1;
  const int l15 = lane & 15, lg = lane >> 4;
  const unsigned short* xbb = xb + (long)bt * (16384 * 256);
  const bool zr0 = (y == 0), zr2 = (y == 127);

  f32x4 acc[4][4];
#pragma unroll
  for (int i = 0; i < 4; i++)
#pragma unroll
    for (int j = 0; j < 4; j++) acc[i][j] = f32x4{0.f, 0.f, 0.f, 0.f};

  // stage chunk s into buffer buf (1536 16B slots, 6 per thread)
  auto STAGE = [&](int buf, int s) {
    const int ci0 = s * 32;
    unsigned short* Ab = As + buf * (3 * 128 * 32);
#pragma unroll
    for (int k = 0; k < 6; k++) {
      const int S = k * 256 + tid;
      const int r = k >> 1;                   // k-uniform row index
      const int p = (S >> 2) & 127;
      const int cs = (S & 3) ^ ((p >> 1) & 3);
      if ((r == 0 && zr0) || (r == 2 && zr2)) {
        *(uint4*)(Ab + S * 8) = uint4{0u, 0u, 0u, 0u};
      } else {
        glds16(xbb + ((long)((y + r - 1) * 128 + p) * 256 + ci0 + cs * 8),
               Ab + (k * 256 + wid * 64) * 8);
      }
    }
  };

  STAGE(0, 0);
  __syncthreads();

  for (int s = 0; s < 8; s++) {
    const int cur = s & 1;
    if (s < 7) STAGE(cur ^ 1, s + 1);
    const unsigned short* Ab = As + cur * (3 * 128 * 32);
    // ---- 9 taps x 16 MFMA on chunk s ----
#pragma unroll
    for (int r = 0; r < 3; r++) {
#pragma unroll
      for (int dxi = 0; dxi < 3; dxi++) {
        const int t = r * 3 + dxi, dx = dxi - 1;
        const unsigned short* wb = wT + (((long)t * 8 + s) * 256) * 32;
        bf16x8 a[4], b[4];
#pragma unroll
        for (int i = 0; i < 4; i++) {
          const int co_r = c0 + wc * 64 + i * 16 + l15;
          b[i] = *(const bf16x8*)(wb + co_r * 32 + lg * 8);
          const int px = wr * 64 + i * 16 + l15 + dx;
          const int pxc = min(127, max(0, px));
          bf16x8 v = *(const bf16x8*)(
              Ab + ((r * 128 + pxc) * 4 + (lg ^ ((pxc >> 1) & 3))) * 8);
          if ((unsigned)px >= 128u) v = bf16x8{0, 0, 0, 0, 0, 0, 0, 0};
          a[i] = v;
        }
#pragma unroll
        for (int mi = 0; mi < 4; mi++)
#pragma unroll
          for (int nj = 0; nj < 4; nj++)
            acc[mi][nj] = __builtin_amdgcn_mfma_f32_16x16x32_bf16(
                a[mi], b[nj], acc[mi][nj], 0, 0, 0);
      }
    }
    __syncthreads();   // drains next-chunk glds (hidden under the MFMAs above)
  }

#pragma unroll
  for (int mi = 0; mi < 4; mi++)
#pragma unroll
    for (int nj = 0; nj < 4; nj++) {
      int co = c0 + wc * 64 + nj * 16 + l15;
      float bb = bias[co];
#pragma unroll
      for (int rr = 0; rr < 4; rr++) {
        int x = wr * 64 + mi * 16 + lg * 4 + rr;
        long idx = ((long)bt * 16384 + y * 128 + x) * 256 + co;
        float v = b2f(mc[idx]) + fmaxf(acc[mi][nj][rr] + bb, 0.f);
        mc[idx] = f2b(v);
      }
    }
}

// ---------------------------------------------------------------------------
// Deformable-attention sampling + fused softmax.
// 64 threads per query: h = t>>3 (8 heads), d4 = t&7 (4 channels each).
// ---------------------------------------------------------------------------
__global__ __launch_bounds__(256) void deform_sample(
    const float* __restrict__ offp, const float* __restrict__ awlog,
    const unsigned short* __restrict__ vp, unsigned short* __restrict__ attn)
{
  const int m = blockIdx.x * 4 + (threadIdx.x >> 6);
  const int t = threadIdx.x & 63;
  const int h = t >> 3, d4 = t & 7;
  const int bt = m / kLQ, q = m % kLQ;
  int pq, Wq;
  if (q < 256)       { pq = q;        Wq = 16; }
  else if (q < 1280) { pq = q - 256;  Wq = 32; }
  else               { pq = q - 1280; Wq = 64; }
  const float refx = ((pq % Wq) + 0.5f) / Wq;
  const float refy = ((pq / Wq) + 0.5f) / Wq;
  const int starts[3] = {0, 256, 1280};
  const int dims[3]   = {16, 32, 64};

  const float4* offr = (const float4*)(offp + (long)m * 192 + h * 24);
  const float4* awr  = (const float4*)(awlog + (long)m * 96 + h * 12);
  float off[24], aw[12];
#pragma unroll
  for (int j = 0; j < 6; j++) {
    float4 v = offr[j];
    off[j * 4] = v.x; off[j * 4 + 1] = v.y; off[j * 4 + 2] = v.z; off[j * 4 + 3] = v.w;
  }
#pragma unroll
  for (int j = 0; j < 3; j++) {
    float4 v = awr[j];
    aw[j * 4] = v.x; aw[j * 4 + 1] = v.y; aw[j * 4 + 2] = v.z; aw[j * 4 + 3] = v.w;
  }
  float mx = aw[0];
#pragma unroll
  for (int j = 1; j < 12; j++) mx = fmaxf(mx, aw[j]);
  float ssum = 0.f;
#pragma unroll
  for (int j = 0; j < 12; j++) { float e = __expf(aw[j] - mx); aw[j] = e; ssum += e; }
  float inv = 1.f / ssum;

  const unsigned short* vb = vp + ((long)bt * kLQ) * 256 + h * 32 + d4 * 4;
  float ax = 0.f, ay = 0.f, az = 0.f, aww = 0.f;
#pragma unroll
  for (int l = 0; l < 3; l++) {
    const int Wl = dims[l];
    const float winv = 1.f / (float)Wl;
    const int st = starts[l];
#pragma unroll
    for (int p = 0; p < 4; p++) {
      float ox = off[l * 8 + p * 2], oy = off[l * 8 + p * 2 + 1];
      float a  = aw[l * 4 + p] * inv;
      float fxp = (refx + ox * winv) * Wl - 0.5f;
      float fyp = (refy + oy * winv) * Wl - 0.5f;
      float x0f = floorf(fxp), y0f = floorf(fyp);
      int x0 = (int)x0f, y0 = (int)y0f;
      float fx = fxp - x0f, fy = fyp - y0f;
      float sx = 0.f, sy = 0.f, sz = 0.f, sw = 0.f;
#pragma unroll
      for (int cy = 0; cy < 2; cy++)
#pragma unroll
        for (int cx = 0; cx < 2; cx++) {
          int ix = x0 + cx, iy = y0 + cy;
          if ((unsigned)ix < (unsigned)Wl && (unsigned)iy < (unsigned)Wl) {
            float w = (cx ? fx : 1.f - fx) * (cy ? fy : 1.f - fy);
            ushort4 u = *(const ushort4*)(vb + (long)(st + iy * Wl + ix) * 256);
            sx += w * b2f(u.x); sy += w * b2f(u.y);
            sz += w * b2f(u.z); sw += w * b2f(u.w);
          }
        }
      ax += a * sx; ay += a * sy; az += a * sz; aww += a * sw;
    }
  }
  ushort4 r;
  r.x = f2b(ax); r.y = f2b(ay); r.z = f2b(az); r.w = f2b(aww);
  *(ushort4*)(attn + (long)m * 256 + h * 32 + d4 * 4) = r;
}

// ---------------------------------------------------------------------------
// LN: one wave per row, float4 per lane, shfl_xor butterfly (no LDS).
// ---------------------------------------------------------------------------
template<bool QB>
__global__ __launch_bounds__(256) void ln_row(
    float* __restrict__ out, const float* __restrict__ delta,
    const float* __restrict__ g, const float* __restrict__ b,
    unsigned short* __restrict__ ob, const float* __restrict__ posf,
    unsigned short* __restrict__ qb)
{
  const long m = blockIdx.x * 4 + (threadIdx.x >> 6);
  const int lane = threadIdx.x & 63;
  const long base = m * 256 + lane * 4;
  float4 a = *(const float4*)(out + base);
  float4 d = *(const float4*)(delta + base);
  float x0 = a.x + d.x, x1 = a.y + d.y, x2 = a.z + d.z, x3 = a.w + d.w;
  float s = x0 + x1 + x2 + x3;
#pragma unroll
  for (int o = 32; o > 0; o >>= 1) s += __shfl_xor(s, o);
  float mean = s * (1.f / 256.f);
  float d0 = x0 - mean, d1 = x1 - mean, d2 = x2 - mean, d3 = x3 - mean;
  float s2 = d0 * d0 + d1 * d1 + d2 * d2 + d3 * d3;
#pragma unroll
  for (int o = 32; o > 0; o >>= 1) s2 += __shfl_xor(s2, o);
  float rs = rsqrtf(s2 * (1.f / 256.f) + 1e-5f);
  float4 gv = *(const float4*)(g + lane * 4);
  float4 bv = *(const float4*)(b + lane * 4);
  float r0 = d0 * rs * gv.x + bv.x, r1 = d1 * rs * gv.y + bv.y;
  float r2 = d2 * rs * gv.z + bv.z, r3 = d3 * rs * gv.w + bv.w;
  *(float4*)(out + base) = float4{r0, r1, r2, r3};
  ushort4 o4; o4.x = f2b(r0); o4.y = f2b(r1); o4.z = f2b(r2); o4.w = f2b(r3);
  *(ushort4*)(ob + base) = o4;
  if (QB) {
    float4 pf = *(const float4*)(posf + base);
    ushort4 q4;
    q4.x = f2b(r0 + pf.x); q4.y = f2b(r1 + pf.y);
    q4.z = f2b(r2 + pf.z); q4.w = f2b(r3 + pf.w);
    *(ushort4*)(qb + base) = q4;
  }
}

// weight transpose+convert+pad: outT[l][n][k] = n<N ? bf16(in[l][k][n]) : 0
__global__ __launch_bounds__(256) void wtrans_pad(
    const float* __restrict__ in, unsigned short* __restrict__ outT,
    int K, int N, int Npad)
{
  int idx = blockIdx.x * 256 + threadIdx.x;
  if (idx >= Npad * K) return;
  int n = idx / K, k = idx % K;
  unsigned short v = 0;
  if (n < N) v = f2b(in[(long)blockIdx.z * K * N + (long)k * N + n]);
  outT[(long)blockIdx.z * Npad * K + idx] = v;
}

__global__ __launch_bounds__(256) void wconvert(
    const float* __restrict__ in, unsigned short* __restrict__ out, int n)
{
  int idx = blockIdx.x * 256 + threadIdx.x;
  if (idx < n) out[idx] = f2b(in[idx]);
}

// outc (6,co,ci,3,3) -> [l][tap][ci-chunk][co][32ci] bf16
__global__ __launch_bounds__(256) void wpermconv(
    const float* __restrict__ in, unsigned short* __restrict__ out)
{
  int idx = blockIdx.x * 256 + threadIdx.x;   // 6*9*256*256 exact
  const int ci = idx & 255;
  const int co = (idx >> 8) & 255;
  const int t  = (idx >> 16) % 9;
  const int l  = idx / (9 << 16);
  const int s = ci >> 5, cin = ci & 31;
  out[((((long)l * 9 + t) * 8 + s) * 256 + co) * 32 + cin] =
      f2b(in[(((long)l * 256 + co) * 256 + ci) * 9 + t]);
}

// src/pos (bt,C,HW) -> outbuf fp32, ob bf16, qb bf16, posf fp32
__global__ __launch_bounds__(256) void init_level(
    const float* __restrict__ src, const float* __restrict__ pos,
    const float* __restrict__ emb, float* __restrict__ outp,
    float* __restrict__ posf, unsigned short* __restrict__ ob,
    unsigned short* __restrict__ qb, int HW, int start)
{
  __shared__ float t1[32][33];
  __shared__ float t2[32][33];
  const int bt = blockIdx.z;
  const int p0 = blockIdx.x * 32, c0 = blockIdx.y * 32;
  const int tx = threadIdx.x, ty = threadIdx.y;
  const float* sb = src + ((long)bt * 256 + c0) * HW + p0;
  const float* pb = pos + ((long)bt * 256 + c0) * HW + p0;
#pragma unroll
  for (int j = 0; j < 4; j++) {
    int cc = ty + j * 8;
    t1[cc][tx] = sb[(long)cc * HW + tx];
    t2[cc][tx] = pb[(long)cc * HW + tx];
  }
  __syncthreads();
#pragma unroll
  for (int j = 0; j < 4; j++) {
    int pp = ty + j * 8;
    long row = (long)bt * kLQ + start + p0 + pp;
    float v = t1[tx][pp];
    float pv = t2[tx][pp] + emb[c0 + tx];
    outp[row * 256 + c0 + tx] = v;
    ob[row * 256 + c0 + tx] = f2b(v);
    qb[row * 256 + c0 + tx] = f2b(v + pv);
    posf[row * 256 + c0 + tx] = pv;
  }
}

// mask_in (b,c,t,128,128) -> mc bf16 NHWC [bt][16384][256]
__global__ __launch_bounds__(256) void init_mask(
    const float* __restrict__ in, unsigned short* __restrict__ mc)
{
  __shared__ float t[32][33];
  const int bt = blockIdx.z, b = bt >> 1, tt = bt & 1;
  const int p0 = blockIdx.x * 32, c0 = blockIdx.y * 32;
  const int tx = threadIdx.x, ty = threadIdx.y;
  const float* base = in + (((long)b * 256 + c0) * 2 + tt) * 16384 + p0;
#pragma unroll
  for (int j = 0; j < 4; j++) {
    int cc = ty + j * 8;
    t[cc][tx] = base[(long)cc * 32768 + tx];
  }
  __syncthreads();
#pragma unroll
  for (int j = 0; j < 4; j++) {
    int pp = ty + j * 8;
    long idx = ((long)bt * 16384 + p0 + pp) * 256 + c0 + tx;
    mc[idx] = f2b(t[tx][pp]);
  }
}

// mc (bf16 NHWC) -> d_out mask region (b,c,t,128,128) fp32
__global__ __launch_bounds__(256) void hwc_to_out(
    const unsigned short* __restrict__ mc, float* __restrict__ outm)
{
  __shared__ float t[32][33];
  const int bt = blockIdx.z, b = bt >> 1, tt = bt & 1;
  const int p0 = blockIdx.x * 32, c0 = blockIdx.y * 32;
  const int tx = threadIdx.x, ty = threadIdx.y;
#pragma unroll
  for (int j = 0; j < 4; j++) {
    int pp = ty + j * 8;
    t[pp][tx] = b2f(mc[((long)bt * 16384 + p0 + pp) * 256 + c0 + tx]);
  }
  __syncthreads();
#pragma unroll
  for (int j = 0; j < 4; j++) {
    int cc = ty + j * 8;
    outm[(((long)b * 256 + c0 + cc) * 2 + tt) * 16384 + p0 + tx] = t[tx][cc];
  }
}

// ---------------------------------------------------------------------------
extern "C" void kernel_launch(void* const* d_in, const int* in_sizes, int n_in,
                              void* d_out, int out_size, void* d_ws, size_t ws_size,
                              hipStream_t stream)
{
  const float* src[3] = {(const float*)d_in[0], (const float*)d_in[2], (const float*)d_in[4]};
  const float* pos[3] = {(const float*)d_in[1], (const float*)d_in[3], (const float*)d_in[5]};
  const float* mask_in = (const float*)d_in[6];
  const float* lemb    = (const float*)d_in[7];
  const float* off_w   = (const float*)d_in[8];
  const float* off_b   = (const float*)d_in[9];
  const float* aw_w    = (const float*)d_in[10];
  const float* aw_b    = (const float*)d_in[11];
  const float* val_w   = (const float*)d_in[12];
  const float* val_b   = (const float*)d_in[13];
  const float* out_w   = (const float*)d_in[14];
  const float* out_b   = (const float*)d_in[15];
  const float* ln1_g   = (const float*)d_in[16];
  const float* ln1_b   = (const float*)d_in[17];
  const float* ff1_w   = (const float*)d_in[18];
  const float* ff1_b   = (const float*)d_in[19];
  const float* ff2_w   = (const float*)d_in[20];
  const float* ff2_b   = (const float*)d_in[21];
  const float* ln2_g   = (const float*)d_in[22];
  const float* ln2_b   = (const float*)d_in[23];
  const float* lat_w   = (const float*)d_in[24];
  const float* lat_b   = (const float*)d_in[25];
  const float* outc_w  = (const float*)d_in[26];
  const float* outc_b  = (const float*)d_in[27];

  float* outbuf = (float*)d_out;                    // (4,5376,256)
  float* maskf  = (float*)d_out + 5505024;          // (2,256,2,128,128)

  char* wp = (char*)d_ws;
  auto alloc = [&](size_t bytes) {
    char* p = wp;
    wp += (bytes + 255) & ~(size_t)255;
    return p;
  };
  float*          posf  = (float*)alloc(5505024ull * 4);
  unsigned short* qb    = (unsigned short*)alloc(5505024ull * 2);
  unsigned short* ob    = (unsigned short*)alloc(5505024ull * 2);
  unsigned short* vbuf  = (unsigned short*)alloc(5505024ull * 2);
  float*          offb  = (float*)alloc(4128768ull * 4);
  float*          awb   = (float*)alloc(2064384ull * 4);
  unsigned short* attnb = (unsigned short*)alloc(5505024ull * 2);
  float*          tmp1  = (float*)alloc(5505024ull * 4);
  unsigned short* ffh   = (unsigned short*)alloc(22020096ull * 2);
  unsigned short* mc    = (unsigned short*)alloc(16777216ull * 2);
  unsigned short* xb    = (unsigned short*)alloc(16777216ull * 2);
  unsigned short* valT  = (unsigned short*)alloc(6ull * 65536 * 2);
  unsigned short* offT  = (unsigned short*)alloc(6ull * 65536 * 2);
  unsigned short* awT   = (unsigned short*)alloc(6ull * 32768 * 2);
  unsigned short* outT  = (unsigned short*)alloc(6ull * 65536 * 2);
  unsigned short* ff1T  = (unsigned short*)alloc(6ull * 262144 * 2);
  unsigned short* ff2T  = (unsigned short*)alloc(6ull * 262144 * 2);
  unsigned short* latT  = (unsigned short*)alloc(6ull * 65536 * 2);
  unsigned short* outcT = (unsigned short*)alloc(6ull * 589824 * 2);

  // ---- weight prep ----
  wtrans_pad<<<dim3(256, 1, 6), 256, 0, stream>>>(val_w, valT, 256, 256, 256);
  wtrans_pad<<<dim3(256, 1, 6), 256, 0, stream>>>(off_w, offT, 256, 192, 256);
  wtrans_pad<<<dim3(128, 1, 6), 256, 0, stream>>>(aw_w,  awT,  256, 96, 128);
  wtrans_pad<<<dim3(256, 1, 6), 256, 0, stream>>>(out_w, outT, 256, 256, 256);
  wtrans_pad<<<dim3(1024, 1, 6), 256, 0, stream>>>(ff1_w, ff1T, 256, 1024, 1024);
  wtrans_pad<<<dim3(1024, 1, 6), 256, 0, stream>>>(ff2_w, ff2T, 1024, 256, 256);
  wconvert<<<dim3(1536), 256, 0, stream>>>(lat_w, latT, 6 * 65536);
  wpermconv<<<dim3(13824), 256, 0, stream>>>(outc_w, outcT);

  // ---- init ----
  const int hw[3] = {256, 1024, 4096};
  const int st[3] = {0, 256, 1280};
  for (int l = 0; l < 3; l++)
    init_level<<<dim3(hw[l] / 32, 8, 4), dim3(32, 8), 0, stream>>>(
        src[l], pos[l], lemb + l * 256, outbuf, posf, ob, qb, hw[l], st[l]);
  init_mask<<<dim3(512, 8, 4), dim3(32, 8), 0, stream>>>(mask_in, mc);

  // ---- layers ----
  for (int i = 0; i < 6; i++) {
    gemm128<1><<<dim3(168, 2), 256, 0, stream>>>(
        ob, valT + (long)i * 65536, val_b + i * 256, vbuf, 21504, 256, 256, nullptr);
    gemm128<0><<<dim3(168, 2), 256, 0, stream>>>(
        qb, offT + (long)i * 65536, off_b + i * 192, offb, 21504, 192, 256, nullptr);
    gemm128<0><<<dim3(168, 1), 256, 0, stream>>>(
        qb, awT + (long)i * 32768, aw_b + i * 96, awb, 21504, 96, 256, nullptr);
    deform_sample<<<dim3(5376), 256, 0, stream>>>(offb, awb, vbuf, attnb);
    gemm128<0><<<dim3(168, 2), 256, 0, stream>>>(
        attnb, outT + (long)i * 65536, out_b + i * 256, tmp1, 21504, 256, 256, nullptr);
    ln_row<false><<<dim3(5376), 256, 0, stream>>>(
        outbuf, tmp1, ln1_g + i * 256, ln1_b + i * 256, ob, nullptr, nullptr);
    gemm128<2><<<dim3(168, 8), 256, 0, stream>>>(
        ob, ff1T + (long)i * 262144, ff1_b + i * 1024, ffh, 21504, 1024, 256, nullptr);
    gemm128<0><<<dim3(168, 2), 256, 0, stream>>>(
        ffh, ff2T + (long)i * 262144, ff2_b + i * 256, tmp1, 21504, 256, 1024, nullptr);
    ln_row<true><<<dim3(5376), 256, 0, stream>>>(
        outbuf, tmp1, ln2_g + i * 256, ln2_b + i * 256, ob, posf, qb);
    // FPN: lat 1x1 conv + fused bilinear resize-add -> xb; 3x3 conv -> mc
    gemm128<3><<<dim3(512, 2), 256, 0, stream>>>(
        mc, latT + (long)i * 65536, lat_b + i * 256, xb, 65536, 256, 256, outbuf);
    conv3x3<<<dim3(128, 2, 4), 256, 0, stream>>>(
        xb, outcT + (long)i * 589824, outc_b + i * 256, mc);
  }
  hwc_to_out<<<dim3(512, 8, 4), dim3(32, 8), 0, stream>>>(mc, maskf);
}